// Round 1
// baseline (441.785 us; speedup 1.0000x reference)
//
#include <hip/hip_runtime.h>
#include <cstdint>

typedef __attribute__((ext_vector_type(8))) short short8;
typedef __attribute__((ext_vector_type(4))) float f32x4;

__device__ inline unsigned short f2bf(float f){
  union { float f; uint32_t u; } v; v.f = f;
  uint32_t r = v.u + 0x7FFFu + ((v.u >> 16) & 1u);
  return (unsigned short)(r >> 16);
}

#define GLL(gp, lp) __builtin_amdgcn_global_load_lds(              \
    (const __attribute__((address_space(1))) void*)(gp),           \
    (__attribute__((address_space(3))) void*)(lp), 16, 0, 0)

// ---------------- kernel 1: weight conversions --------------------------
// Wb  : bf16 [1024][1024]  = W_base
// BTt : bf16 [1024][32]    BTt[o][e*4+r] = B[e][r][o]
// W2T : f32  [40][1024]    rows 0..31 = A[e][d][r] (n=e*4+r), rows 32..39 = W_router
__global__ __launch_bounds__(256) void kconv(const float* __restrict__ W,
                                             const float* __restrict__ Wr,
                                             const float* __restrict__ A,
                                             const float* __restrict__ Bm,
                                             unsigned short* __restrict__ Wb,
                                             unsigned short* __restrict__ BTt,
                                             float* __restrict__ W2T){
  int i = blockIdx.x * 256 + threadIdx.x;          // grid = exactly 1M threads
  Wb[i] = f2bf(W[i]);
  if (i < 32768){ int o = i >> 5, c = i & 31; BTt[i] = f2bf(Bm[(size_t)c*1024 + o]); }
  if (i < 40960){
    int n = i >> 10, d = i & 1023;
    float v = (n < 32) ? A[((size_t)(n>>2)*1024 + d)*4 + (n&3)]
                       : Wr[(size_t)(n-32)*1024 + d];
    W2T[i] = v;
  }
}

// ---------------- kernel 2: router + low-rank h + gating ----------------
// Per block: 16 tokens. thread = (token t = tid>>4, col-group h = tid&15)
// computes HGL[t][n] for n in {h, h+16, h+32(h<8)}; then 16 threads do
// softmax/top2/renorm and write HG bf16 [16384][32]. Optionally emits xb bf16.
__global__ __launch_bounds__(256) void khgl(const float* __restrict__ x,
                                            const float* __restrict__ W2T,
                                            unsigned short* __restrict__ HG,
                                            unsigned short* __restrict__ xb){
  __shared__ float hbuf[16][40];
  const int tid = threadIdx.x;
  const int blk = blockIdx.x;
  const int t = tid >> 4;
  const int h = tid & 15;
  const size_t tok = (size_t)blk*16 + t;
  const float4* __restrict__ xr = (const float4*)(x + tok*1024);
  const float4* __restrict__ w0 = (const float4*)(W2T + (size_t)h*1024);
  const float4* __restrict__ w1 = (const float4*)(W2T + (size_t)(h+16)*1024);
  const float4* __restrict__ w2 = (const float4*)(W2T + (size_t)((h&7)+32)*1024);
  float a0=0.f, a1=0.f, a2=0.f;
  #pragma unroll 4
  for (int k=0;k<256;k++){
    float4 xv = xr[k];
    float4 p = w0[k]; a0 += xv.x*p.x + xv.y*p.y + xv.z*p.z + xv.w*p.w;
    float4 q = w1[k]; a1 += xv.x*q.x + xv.y*q.y + xv.z*q.z + xv.w*q.w;
    float4 r = w2[k]; a2 += xv.x*r.x + xv.y*r.y + xv.z*r.z + xv.w*r.w;
  }
  hbuf[t][h]    = a0;
  hbuf[t][h+16] = a1;
  if (h < 8) hbuf[t][h+32] = a2;

  if (xb){  // bf16 copy of x for the GEMM's A staging
    const float4* xs = (const float4*)(x + (size_t)blk*16384);
    ushort4* xd = (ushort4*)(xb + (size_t)blk*16384);
    #pragma unroll
    for (int j=0;j<16;j++){
      float4 v = xs[j*256 + tid];
      ushort4 o4; o4.x=f2bf(v.x); o4.y=f2bf(v.y); o4.z=f2bf(v.z); o4.w=f2bf(v.w);
      xd[j*256 + tid] = o4;
    }
  }
  __syncthreads();
  if (tid < 16){
    const float* row = hbuf[tid];
    const float* lg  = row + 32;
    float mx = lg[0];
    #pragma unroll
    for (int e=1;e<8;e++) mx = fmaxf(mx, lg[e]);
    float ex[8], s = 0.f;
    #pragma unroll
    for (int e=0;e<8;e++){ ex[e] = __expf(lg[e]-mx); s += ex[e]; }
    int i1 = 0; float v1 = ex[0];
    #pragma unroll
    for (int e=1;e<8;e++) if (ex[e] > v1){ v1 = ex[e]; i1 = e; }
    int i2 = -1; float v2 = -1.f;
    #pragma unroll
    for (int e=0;e<8;e++) if (e != i1 && ex[e] > v2){ v2 = ex[e]; i2 = e; }
    float g1 = v1/s, g2 = v2/s;
    float rs = 1.f/(g1 + g2 + 1e-6f);
    size_t tk = (size_t)blk*16 + tid;
    unsigned short* o = HG + tk*32;
    #pragma unroll
    for (int e=0;e<8;e++){
      float ge = (e==i1 ? g1 : (e==i2 ? g2 : 0.f)) * rs;
      #pragma unroll
      for (int r2=0;r2<4;r2++) o[e*4+r2] = f2bf(row[e*4+r2]*ge);
    }
  }
}

// ---------------- kernel 3: fused GEMM  out = X@W^T + b + HG@B ----------
// 128x128 tile, 4 waves (2x2 of 64x64), BK=32, bf16 16x16x32 MFMA.
// A staged from xb (bf16) if XB else from x (f32, converted at frag load).
// LoRA: one extra K=32 MFMA step from HG[128][32] x BTt[128][32].
template<bool XB>
__global__ __launch_bounds__(256) void kgemm(const float* __restrict__ x,
                                             const unsigned short* __restrict__ xbp,
                                             const unsigned short* __restrict__ Wb,
                                             const unsigned short* __restrict__ BTt,
                                             const unsigned short* __restrict__ HG,
                                             const float* __restrict__ bias,
                                             float* __restrict__ out){
  constexpr int ABYTES = XB ? 8192 : 16384;
  __shared__ char lds[ABYTES + 8192];
  const int tid  = threadIdx.x;
  const int lane = tid & 63;
  const int wv   = tid >> 6;
  const int nblk = blockIdx.x & 7;       // fastest dim -> XCD-affine W panels
  const int mblk = blockIdx.x >> 3;
  const int m0 = mblk*128, n0 = nblk*128;
  const int wm = wv >> 1, wn = wv & 1;
  const int lrow = lane & 15;
  const int lk   = (lane >> 4) * 8;

  f32x4 acc[4][4];
  #pragma unroll
  for (int a=0;a<4;a++)
    #pragma unroll
    for (int b=0;b<4;b++) acc[a][b] = (f32x4){0.f,0.f,0.f,0.f};

  for (int kt=0;kt<32;kt++){
    __syncthreads();
    const int k0 = kt*32;
    if constexpr (XB){
      #pragma unroll
      for (int i=0;i<2;i++){
        int off = (wv*2+i)*1024 + lane*16;
        int row = off >> 6, colb = off & 63;
        GLL(xbp + (size_t)(m0+row)*1024 + k0 + (colb>>1), lds + off);
      }
    } else {
      #pragma unroll
      for (int i=0;i<4;i++){
        int off = (wv*4+i)*1024 + lane*16;
        int row = off >> 7, colb = off & 127;
        GLL(x + (size_t)(m0+row)*1024 + k0 + (colb>>2), lds + off);
      }
    }
    #pragma unroll
    for (int i=0;i<2;i++){
      int off = (wv*2+i)*1024 + lane*16;
      int row = off >> 6, colb = off & 63;
      GLL(Wb + (size_t)(n0+row)*1024 + k0 + (colb>>1), lds + ABYTES + off);
    }
    __syncthreads();

    short8 af[4], bfr[4];
    #pragma unroll
    for (int fm=0;fm<4;fm++){
      int r = wm*64 + fm*16 + lrow;
      if constexpr (XB){
        af[fm] = *(const short8*)(lds + (size_t)(r*32 + lk)*2);
      } else {
        const float* ap = (const float*)lds + r*32 + lk;
        float4 lo = *(const float4*)ap;
        float4 hi = *(const float4*)(ap+4);
        short8 v;
        v[0]=(short)f2bf(lo.x); v[1]=(short)f2bf(lo.y);
        v[2]=(short)f2bf(lo.z); v[3]=(short)f2bf(lo.w);
        v[4]=(short)f2bf(hi.x); v[5]=(short)f2bf(hi.y);
        v[6]=(short)f2bf(hi.z); v[7]=(short)f2bf(hi.w);
        af[fm] = v;
      }
    }
    #pragma unroll
    for (int fn=0;fn<4;fn++){
      int r = wn*64 + fn*16 + lrow;
      bfr[fn] = *(const short8*)(lds + ABYTES + (size_t)(r*32 + lk)*2);
    }
    #pragma unroll
    for (int fm=0;fm<4;fm++)
      #pragma unroll
      for (int fn=0;fn<4;fn++)
        acc[fm][fn] = __builtin_amdgcn_mfma_f32_16x16x32_bf16(af[fm], bfr[fn], acc[fm][fn], 0, 0, 0);
  }

  // ---- LoRA K=32 step: out += HG[m][0:32] @ BTt[n][0:32]^T ----
  __syncthreads();
  #pragma unroll
  for (int i=0;i<2;i++){
    int off = (wv*2+i)*1024 + lane*16;
    GLL((const char*)HG  + (size_t)m0*64 + off, lds + off);
    GLL((const char*)BTt + (size_t)n0*64 + off, lds + ABYTES + off);
  }
  __syncthreads();
  {
    short8 ah[4], bh[4];
    #pragma unroll
    for (int fm=0;fm<4;fm++){
      int r = wm*64 + fm*16 + lrow;
      ah[fm] = *(const short8*)(lds + (size_t)(r*32 + lk)*2);
    }
    #pragma unroll
    for (int fn=0;fn<4;fn++){
      int r = wn*64 + fn*16 + lrow;
      bh[fn] = *(const short8*)(lds + ABYTES + (size_t)(r*32 + lk)*2);
    }
    #pragma unroll
    for (int fm=0;fm<4;fm++)
      #pragma unroll
      for (int fn=0;fn<4;fn++)
        acc[fm][fn] = __builtin_amdgcn_mfma_f32_16x16x32_bf16(ah[fm], bh[fn], acc[fm][fn], 0, 0, 0);
  }

  // ---- epilogue: + bias, store f32 ----
  #pragma unroll
  for (int fn=0;fn<4;fn++){
    int col = n0 + wn*64 + fn*16 + lrow;
    float bv = bias[col];
    #pragma unroll
    for (int fm=0;fm<4;fm++){
      int rb = m0 + wm*64 + fm*16 + (lane>>4)*4;
      #pragma unroll
      for (int j=0;j<4;j++)
        out[(size_t)(rb+j)*1024 + col] = acc[fm][fn][j] + bv;
    }
  }
}

// ---------------- host ---------------------------------------------------
extern "C" void kernel_launch(void* const* d_in, const int* in_sizes, int n_in,
                              void* d_out, int out_size, void* d_ws, size_t ws_size,
                              hipStream_t stream){
  const float* x  = (const float*)d_in[0];
  const float* W  = (const float*)d_in[1];
  const float* bb = (const float*)d_in[2];
  const float* Wr = (const float*)d_in[3];
  const float* A  = (const float*)d_in[4];
  const float* Bm = (const float*)d_in[5];
  float* out = (float*)d_out;
  char* ws = (char*)d_ws;

  // ws layout (bytes): Wb 2MB | BTt 64KB | W2T 160KB | HG 1MB | [xb 32MB]
  unsigned short* Wb  = (unsigned short*)(ws + 0);
  unsigned short* BTt = (unsigned short*)(ws + 2097152);
  float*          W2T = (float*)         (ws + 2162688);
  unsigned short* HG  = (unsigned short*)(ws + 2326528);
  unsigned short* xb  = (unsigned short*)(ws + 3375104);
  bool use_xb = ws_size >= (3375104ull + 33554432ull);

  kconv<<<4096, 256, 0, stream>>>(W, Wr, A, Bm, Wb, BTt, W2T);
  khgl<<<1024, 256, 0, stream>>>(x, W2T, HG, use_xb ? xb : nullptr);
  if (use_xb) kgemm<true ><<<1024, 256, 0, stream>>>(x, xb, Wb, BTt, HG, bb, out);
  else        kgemm<false><<<1024, 256, 0, stream>>>(x, nullptr, Wb, BTt, HG, bb, out);
}

// Round 2
// 127.587 us; speedup vs baseline: 3.4626x; 3.4626x over previous
//
#include <hip/hip_runtime.h>
#include <cstdint>

typedef __attribute__((ext_vector_type(8))) short short8;
typedef __attribute__((ext_vector_type(4))) float f32x4;

__device__ inline unsigned short f2bf(float f){
  union { float f; uint32_t u; } v; v.f = f;
  uint32_t r = v.u + 0x7FFFu + ((v.u >> 16) & 1u);
  return (unsigned short)(r >> 16);
}

#define GLL(gp, lp) __builtin_amdgcn_global_load_lds(              \
    (const __attribute__((address_space(1))) void*)(gp),           \
    (__attribute__((address_space(3))) void*)(lp), 16, 0, 0)

// ---------------- kernel 1: weight conversions --------------------------
// Wb  : bf16 [1024][1024] = W_base
// BTt : bf16 [1024][32]   BTt[o][e*4+r] = B[e][r][o]
// W2b : bf16 [32][1024]   W2b[e*4+r][d] = A[e][d][r]
__global__ __launch_bounds__(256) void kconv(const float* __restrict__ W,
                                             const float* __restrict__ A,
                                             const float* __restrict__ Bm,
                                             unsigned short* __restrict__ Wb,
                                             unsigned short* __restrict__ BTt,
                                             unsigned short* __restrict__ W2b){
  int i = blockIdx.x * 256 + threadIdx.x;          // grid = exactly 1M threads
  Wb[i] = f2bf(W[i]);
  if (i < 32768){
    int o = i >> 5, c = i & 31;
    BTt[i] = f2bf(Bm[(size_t)c*1024 + o]);
    int n = i >> 10, d = i & 1023;
    W2b[i] = f2bf(A[(((size_t)(n>>2))*1024 + d)*4 + (n&3)]);
  }
}

// ---------------- kernel 2: x->bf16 + f32 router logits + gating --------
// 16 tokens/block. Iteration j: whole block works on token j — each thread
// holds 4 contiguous floats (coalesced), computes 8 expert partials vs
// LDS-staged W_router, wave shfl_xor reduce, cross-wave combine in LDS.
__global__ __launch_bounds__(256) void kxl(const float* __restrict__ x,
                                           const float* __restrict__ Wr,
                                           unsigned short* __restrict__ xb,
                                           float* __restrict__ gate){
  __shared__ float wr[8192];         // 8 x 1024 f32 = 32KB
  __shared__ float red[16][4][8];    // per-token per-wave partials
  const int tid  = threadIdx.x;
  const int lane = tid & 63;
  const int wid  = tid >> 6;
  {
    const float4* s  = (const float4*)Wr;
    float4*       d4 = (float4*)wr;
    #pragma unroll
    for (int j=0;j<8;j++) d4[j*256+tid] = s[j*256+tid];
  }
  __syncthreads();
  const float4* xs  = (const float4*)(x + (size_t)blockIdx.x*16384);
  ushort4*      xd  = xb ? (ushort4*)(xb + (size_t)blockIdx.x*16384) : nullptr;
  const float4* wv4 = (const float4*)wr;
  for (int j=0;j<16;j++){
    float4 xv = xs[j*256 + tid];
    if (xd){
      ushort4 o4; o4.x=f2bf(xv.x); o4.y=f2bf(xv.y); o4.z=f2bf(xv.z); o4.w=f2bf(xv.w);
      xd[j*256 + tid] = o4;
    }
    float p[8];
    #pragma unroll
    for (int e=0;e<8;e++){
      float4 w = wv4[e*256 + tid];
      p[e] = xv.x*w.x + xv.y*w.y + xv.z*w.z + xv.w*w.w;
    }
    #pragma unroll
    for (int off=32; off>0; off>>=1){
      #pragma unroll
      for (int e=0;e<8;e++) p[e] += __shfl_xor(p[e], off, 64);
    }
    if (lane == 0){
      #pragma unroll
      for (int e=0;e<8;e++) red[j][wid][e] = p[e];
    }
  }
  __syncthreads();
  if (tid < 128){
    int t = tid>>3, e = tid&7;
    red[t][0][e] += red[t][1][e] + red[t][2][e] + red[t][3][e];
  }
  __syncthreads();
  if (tid < 16){
    float lg[8];
    #pragma unroll
    for (int e=0;e<8;e++) lg[e] = red[tid][0][e];
    float mx = lg[0];
    #pragma unroll
    for (int e=1;e<8;e++) mx = fmaxf(mx, lg[e]);
    float ex[8], s = 0.f;
    #pragma unroll
    for (int e=0;e<8;e++){ ex[e] = __expf(lg[e]-mx); s += ex[e]; }
    int i1 = 0; float v1 = ex[0];
    #pragma unroll
    for (int e=1;e<8;e++) if (ex[e] > v1){ v1 = ex[e]; i1 = e; }
    int i2 = -1; float v2 = -1.f;
    #pragma unroll
    for (int e=0;e<8;e++) if (e != i1 && ex[e] > v2){ v2 = ex[e]; i2 = e; }
    float g1 = v1/s, g2 = v2/s;
    float rs = 1.f/(g1 + g2 + 1e-6f);
    float* go = gate + ((size_t)blockIdx.x*16 + tid)*8;
    #pragma unroll
    for (int e=0;e<8;e++) go[e] = (e==i1 ? g1 : (e==i2 ? g2 : 0.f)) * rs;
  }
}

// ---------------- kernel 3: HG = (x @ A) * gate via MFMA ----------------
// M=16384, N=32, K=1024. One wave per 16 tokens, no LDS, no barriers:
// A-frags streamed from xb (bf16) or x (f32, converted), B-frags (W2b rows,
// 64KB) served from L2. Epilogue scales by gate and stores HG bf16.
template<bool BF>
__global__ __launch_bounds__(256) void kh(const void* __restrict__ xsrc,
                                          const unsigned short* __restrict__ W2b,
                                          const float* __restrict__ gate,
                                          unsigned short* __restrict__ HG){
  const int tid  = threadIdx.x;
  const int lane = tid & 63;
  const int wid  = tid >> 6;
  const int lrow = lane & 15;
  const int lk   = (lane >> 4) * 8;
  const int tok0 = blockIdx.x*64 + wid*16;
  f32x4 acc0 = {0.f,0.f,0.f,0.f}, acc1 = {0.f,0.f,0.f,0.f};
  const unsigned short* b0 = W2b + (size_t)lrow*1024 + lk;
  const unsigned short* b1 = W2b + (size_t)(16+lrow)*1024 + lk;
  const unsigned short* arow_b = (const unsigned short*)xsrc + (size_t)(tok0+lrow)*1024 + lk;
  const float*          arow_f = (const float*)xsrc          + (size_t)(tok0+lrow)*1024 + lk;
  #pragma unroll 4
  for (int ks=0; ks<32; ks++){
    short8 av;
    if constexpr (BF){
      av = *(const short8*)(arow_b + ks*32);
    } else {
      float4 lo = *(const float4*)(arow_f + ks*32);
      float4 hi = *(const float4*)(arow_f + ks*32 + 4);
      av[0]=(short)f2bf(lo.x); av[1]=(short)f2bf(lo.y);
      av[2]=(short)f2bf(lo.z); av[3]=(short)f2bf(lo.w);
      av[4]=(short)f2bf(hi.x); av[5]=(short)f2bf(hi.y);
      av[6]=(short)f2bf(hi.z); av[7]=(short)f2bf(hi.w);
    }
    short8 bv0 = *(const short8*)(b0 + ks*32);
    short8 bv1 = *(const short8*)(b1 + ks*32);
    acc0 = __builtin_amdgcn_mfma_f32_16x16x32_bf16(av, bv0, acc0, 0, 0, 0);
    acc1 = __builtin_amdgcn_mfma_f32_16x16x32_bf16(av, bv1, acc1, 0, 0, 0);
  }
  #pragma unroll
  for (int j=0;j<4;j++){
    int tok = tok0 + (lane>>4)*4 + j;
    float g0 = gate[(size_t)tok*8 + (lrow>>2)];
    float g1 = gate[(size_t)tok*8 + 4 + (lrow>>2)];
    HG[(size_t)tok*32 + lrow]      = f2bf(acc0[j]*g0);
    HG[(size_t)tok*32 + 16 + lrow] = f2bf(acc1[j]*g1);
  }
}

// ---------------- kernel 4: fused GEMM  out = X@W^T + b + HG@B ----------
template<bool XB>
__global__ __launch_bounds__(256) void kgemm(const float* __restrict__ x,
                                             const unsigned short* __restrict__ xbp,
                                             const unsigned short* __restrict__ Wb,
                                             const unsigned short* __restrict__ BTt,
                                             const unsigned short* __restrict__ HG,
                                             const float* __restrict__ bias,
                                             float* __restrict__ out){
  constexpr int ABYTES = XB ? 8192 : 16384;
  __shared__ char lds[ABYTES + 8192];
  const int tid  = threadIdx.x;
  const int lane = tid & 63;
  const int wv   = tid >> 6;
  const int nblk = blockIdx.x & 7;
  const int mblk = blockIdx.x >> 3;
  const int m0 = mblk*128, n0 = nblk*128;
  const int wm = wv >> 1, wn = wv & 1;
  const int lrow = lane & 15;
  const int lk   = (lane >> 4) * 8;

  f32x4 acc[4][4];
  #pragma unroll
  for (int a=0;a<4;a++)
    #pragma unroll
    for (int b=0;b<4;b++) acc[a][b] = (f32x4){0.f,0.f,0.f,0.f};

  for (int kt=0;kt<32;kt++){
    __syncthreads();
    const int k0 = kt*32;
    if constexpr (XB){
      #pragma unroll
      for (int i=0;i<2;i++){
        int off = (wv*2+i)*1024 + lane*16;
        int row = off >> 6, colb = off & 63;
        GLL(xbp + (size_t)(m0+row)*1024 + k0 + (colb>>1), lds + off);
      }
    } else {
      #pragma unroll
      for (int i=0;i<4;i++){
        int off = (wv*4+i)*1024 + lane*16;
        int row = off >> 7, colb = off & 127;
        GLL(x + (size_t)(m0+row)*1024 + k0 + (colb>>2), lds + off);
      }
    }
    #pragma unroll
    for (int i=0;i<2;i++){
      int off = (wv*2+i)*1024 + lane*16;
      int row = off >> 6, colb = off & 63;
      GLL(Wb + (size_t)(n0+row)*1024 + k0 + (colb>>1), lds + ABYTES + off);
    }
    __syncthreads();

    short8 af[4], bfr[4];
    #pragma unroll
    for (int fm=0;fm<4;fm++){
      int r = wm*64 + fm*16 + lrow;
      if constexpr (XB){
        af[fm] = *(const short8*)(lds + (size_t)(r*32 + lk)*2);
      } else {
        const float* ap = (const float*)lds + r*32 + lk;
        float4 lo = *(const float4*)ap;
        float4 hi = *(const float4*)(ap+4);
        short8 v;
        v[0]=(short)f2bf(lo.x); v[1]=(short)f2bf(lo.y);
        v[2]=(short)f2bf(lo.z); v[3]=(short)f2bf(lo.w);
        v[4]=(short)f2bf(hi.x); v[5]=(short)f2bf(hi.y);
        v[6]=(short)f2bf(hi.z); v[7]=(short)f2bf(hi.w);
        af[fm] = v;
      }
    }
    #pragma unroll
    for (int fn=0;fn<4;fn++){
      int r = wn*64 + fn*16 + lrow;
      bfr[fn] = *(const short8*)(lds + ABYTES + (size_t)(r*32 + lk)*2);
    }
    #pragma unroll
    for (int fm=0;fm<4;fm++)
      #pragma unroll
      for (int fn=0;fn<4;fn++)
        acc[fm][fn] = __builtin_amdgcn_mfma_f32_16x16x32_bf16(af[fm], bfr[fn], acc[fm][fn], 0, 0, 0);
  }

  // ---- LoRA K=32 step ----
  __syncthreads();
  #pragma unroll
  for (int i=0;i<2;i++){
    int off = (wv*2+i)*1024 + lane*16;
    GLL((const char*)HG  + (size_t)m0*64 + off, lds + off);
    GLL((const char*)BTt + (size_t)n0*64 + off, lds + ABYTES + off);
  }
  __syncthreads();
  {
    short8 ah[4], bh[4];
    #pragma unroll
    for (int fm=0;fm<4;fm++){
      int r = wm*64 + fm*16 + lrow;
      ah[fm] = *(const short8*)(lds + (size_t)(r*32 + lk)*2);
    }
    #pragma unroll
    for (int fn=0;fn<4;fn++){
      int r = wn*64 + fn*16 + lrow;
      bh[fn] = *(const short8*)(lds + ABYTES + (size_t)(r*32 + lk)*2);
    }
    #pragma unroll
    for (int fm=0;fm<4;fm++)
      #pragma unroll
      for (int fn=0;fn<4;fn++)
        acc[fm][fn] = __builtin_amdgcn_mfma_f32_16x16x32_bf16(ah[fm], bh[fn], acc[fm][fn], 0, 0, 0);
  }

  // ---- epilogue ----
  #pragma unroll
  for (int fn=0;fn<4;fn++){
    int col = n0 + wn*64 + fn*16 + lrow;
    float bv = bias[col];
    #pragma unroll
    for (int fm=0;fm<4;fm++){
      int rb = m0 + wm*64 + fm*16 + (lane>>4)*4;
      #pragma unroll
      for (int j=0;j<4;j++)
        out[(size_t)(rb+j)*1024 + col] = acc[fm][fn][j] + bv;
    }
  }
}

// ---------------- host ---------------------------------------------------
extern "C" void kernel_launch(void* const* d_in, const int* in_sizes, int n_in,
                              void* d_out, int out_size, void* d_ws, size_t ws_size,
                              hipStream_t stream){
  const float* x  = (const float*)d_in[0];
  const float* W  = (const float*)d_in[1];
  const float* bb = (const float*)d_in[2];
  const float* Wr = (const float*)d_in[3];
  const float* A  = (const float*)d_in[4];
  const float* Bm = (const float*)d_in[5];
  float* out = (float*)d_out;
  char* ws = (char*)d_ws;

  // ws layout (bytes): Wb 2MB | BTt 64KB | W2b 64KB | gate 512KB | HG 1MB | xb 32MB
  unsigned short* Wb   = (unsigned short*)(ws + 0);
  unsigned short* BTt  = (unsigned short*)(ws + 2097152);
  unsigned short* W2b  = (unsigned short*)(ws + 2162688);
  float*          gate = (float*)         (ws + 2228224);
  unsigned short* HG   = (unsigned short*)(ws + 2752512);
  unsigned short* xb   = (unsigned short*)(ws + 3801088);
  bool use_xb = ws_size >= (3801088ull + 33554432ull);

  kconv<<<4096, 256, 0, stream>>>(W, A, Bm, Wb, BTt, W2b);
  kxl<<<1024, 256, 0, stream>>>(x, Wr, use_xb ? xb : nullptr, gate);
  if (use_xb){
    kh<true ><<<256, 256, 0, stream>>>(xb, W2b, gate, HG);
    kgemm<true ><<<1024, 256, 0, stream>>>(x, xb, Wb, BTt, HG, bb, out);
  } else {
    kh<false><<<256, 256, 0, stream>>>(x, W2b, gate, HG);
    kgemm<false><<<1024, 256, 0, stream>>>(x, nullptr, Wb, BTt, HG, bb, out);
  }
}

// Round 3
// 97.457 us; speedup vs baseline: 4.5331x; 1.3092x over previous
//
#include <hip/hip_runtime.h>
#include <cstdint>

typedef __attribute__((ext_vector_type(8))) short short8;
typedef __attribute__((ext_vector_type(4))) float f32x4;

__device__ inline unsigned short f2bf(float f){
  union { float f; uint32_t u; } v; v.f = f;
  uint32_t r = v.u + 0x7FFFu + ((v.u >> 16) & 1u);
  return (unsigned short)(r >> 16);
}

#define GLL(gp, lp) __builtin_amdgcn_global_load_lds(              \
    (const __attribute__((address_space(1))) void*)(gp),           \
    (__attribute__((address_space(3))) void*)(lp), 16, 0, 0)

// ---------------- kernel 1: weight conversions --------------------------
// Wb  : bf16 [1024][1024] = W_base
// BTt : bf16 [1024][32]   BTt[o][e*4+r] = B[e][r][o]
// W2b : bf16 [32][1024]   W2b[e*4+r][d] = A[e][d][r]
__global__ __launch_bounds__(256) void kconv(const float* __restrict__ W,
                                             const float* __restrict__ A,
                                             const float* __restrict__ Bm,
                                             unsigned short* __restrict__ Wb,
                                             unsigned short* __restrict__ BTt,
                                             unsigned short* __restrict__ W2b){
  int i = blockIdx.x * 256 + threadIdx.x;          // grid = exactly 1M threads
  Wb[i] = f2bf(W[i]);
  if (i < 32768){
    int o = i >> 5, c = i & 31;
    BTt[i] = f2bf(Bm[(size_t)c*1024 + o]);
    int n = i >> 10, d = i & 1023;
    W2b[i] = f2bf(A[(((size_t)(n>>2))*1024 + d)*4 + (n&3)]);
  }
}

// ---------------- kernel 2: x->bf16 + f32 router + gating ---------------
// Wave-private tokens: wave w owns tokens blk*16 + w*4 + {0..3}. Per token:
// coalesced float4 x loads (+ bf16 emit), 8 expert dots vs LDS W_router,
// one 64-lane shfl reduce, lane0 does softmax/top2/renorm in f32.
__global__ __launch_bounds__(256) void kxl(const float* __restrict__ x,
                                           const float* __restrict__ Wr,
                                           unsigned short* __restrict__ xb,
                                           float* __restrict__ gate){
  __shared__ float wr[8192];         // 8 x 1024 f32 = 32KB
  const int tid  = threadIdx.x;
  const int lane = tid & 63;
  const int w    = tid >> 6;
  {
    const float4* s  = (const float4*)Wr;
    float4*       d4 = (float4*)wr;
    #pragma unroll
    for (int j=0;j<8;j++) d4[j*256+tid] = s[j*256+tid];
  }
  __syncthreads();
  const float4* wr4 = (const float4*)wr;
  #pragma unroll 1
  for (int tt=0; tt<4; tt++){
    const size_t tok = (size_t)blockIdx.x*16 + w*4 + tt;
    const float4* xr = (const float4*)(x + tok*1024);
    ushort4*      xd = (ushort4*)(xb + tok*1024);
    float4 xv[4];
    #pragma unroll
    for (int c=0;c<4;c++){
      xv[c] = xr[c*64 + lane];
      ushort4 o4; o4.x=f2bf(xv[c].x); o4.y=f2bf(xv[c].y);
      o4.z=f2bf(xv[c].z); o4.w=f2bf(xv[c].w);
      xd[c*64 + lane] = o4;
    }
    float p[8];
    #pragma unroll
    for (int e=0;e<8;e++){
      float a = 0.f;
      #pragma unroll
      for (int c=0;c<4;c++){
        float4 wv = wr4[e*256 + c*64 + lane];
        a += xv[c].x*wv.x + xv[c].y*wv.y + xv[c].z*wv.z + xv[c].w*wv.w;
      }
      p[e] = a;
    }
    #pragma unroll
    for (int off=32; off; off>>=1){
      #pragma unroll
      for (int e=0;e<8;e++) p[e] += __shfl_xor(p[e], off, 64);
    }
    if (lane == 0){
      float mx = p[0];
      #pragma unroll
      for (int e=1;e<8;e++) mx = fmaxf(mx, p[e]);
      float ex[8], s2 = 0.f;
      #pragma unroll
      for (int e=0;e<8;e++){ ex[e] = __expf(p[e]-mx); s2 += ex[e]; }
      int i1 = 0; float v1 = ex[0];
      #pragma unroll
      for (int e=1;e<8;e++) if (ex[e] > v1){ v1 = ex[e]; i1 = e; }
      int i2 = -1; float v2 = -1.f;
      #pragma unroll
      for (int e=0;e<8;e++) if (e != i1 && ex[e] > v2){ v2 = ex[e]; i2 = e; }
      float g1 = v1/s2, g2 = v2/s2;
      float rs = 1.f/(g1 + g2 + 1e-6f);
      float* go = gate + tok*8;
      #pragma unroll
      for (int e=0;e<8;e++) go[e] = (e==i1 ? g1 : (e==i2 ? g2 : 0.f)) * rs;
    }
  }
}

// ---------------- kernel 3: HG = (x @ A) * gate via MFMA ----------------
__global__ __launch_bounds__(256) void kh(const unsigned short* __restrict__ xbp,
                                          const unsigned short* __restrict__ W2b,
                                          const float* __restrict__ gate,
                                          unsigned short* __restrict__ HG){
  const int tid  = threadIdx.x;
  const int lane = tid & 63;
  const int wid  = tid >> 6;
  const int lrow = lane & 15;
  const int lk   = (lane >> 4) * 8;
  const int tok0 = blockIdx.x*64 + wid*16;
  f32x4 acc0 = {0.f,0.f,0.f,0.f}, acc1 = {0.f,0.f,0.f,0.f};
  const unsigned short* b0 = W2b + (size_t)lrow*1024 + lk;
  const unsigned short* b1 = W2b + (size_t)(16+lrow)*1024 + lk;
  const unsigned short* ar = xbp + (size_t)(tok0+lrow)*1024 + lk;
  #pragma unroll 4
  for (int ks=0; ks<32; ks++){
    short8 av  = *(const short8*)(ar + ks*32);
    short8 bv0 = *(const short8*)(b0 + ks*32);
    short8 bv1 = *(const short8*)(b1 + ks*32);
    acc0 = __builtin_amdgcn_mfma_f32_16x16x32_bf16(av, bv0, acc0, 0, 0, 0);
    acc1 = __builtin_amdgcn_mfma_f32_16x16x32_bf16(av, bv1, acc1, 0, 0, 0);
  }
  #pragma unroll
  for (int j=0;j<4;j++){
    int tok = tok0 + (lane>>4)*4 + j;
    float g0 = gate[(size_t)tok*8 + (lrow>>2)];
    float g1 = gate[(size_t)tok*8 + 4 + (lrow>>2)];
    HG[(size_t)tok*32 + lrow]      = f2bf(acc0[j]*g0);
    HG[(size_t)tok*32 + 16 + lrow] = f2bf(acc1[j]*g1);
  }
}

// ---------------- kernel 4: 256x256 pipelined GEMM + LoRA epilogue ------
// 8 waves (2Mx4N), BK=32, double-buffered 64KB LDS, 2 phases/K-tile,
// counted vmcnt(4) (never drain mid-loop), XOR bank swizzle applied via
// pre-swizzled global source (linear GLL dest) + same XOR on ds_read.
__global__ __launch_bounds__(512, 2) void kgemm2(const unsigned short* __restrict__ xb,
                                                 const unsigned short* __restrict__ Wb,
                                                 const unsigned short* __restrict__ BTt,
                                                 const unsigned short* __restrict__ HG,
                                                 const float* __restrict__ bias,
                                                 float* __restrict__ out){
  __shared__ char lds[65536];   // A slots @0,@16K ; B slots @32K,@48K
  const int tid  = threadIdx.x;
  const int lane = tid & 63;
  const int w    = tid >> 6;
  const int xcd  = blockIdx.x & 7, jj = blockIdx.x >> 3;
  const int nblk = xcd >> 1;              // 0..3  (B panel L2-resident per XCD pair)
  const int mblk = (xcd & 1) * 32 + jj;   // 0..63
  const int m0 = mblk << 8, n0 = nblk << 8;
  const int wm = w >> 2, wn = w & 3;
  const int lrow = lane & 15;
  const int lkb  = (lane >> 4) << 4;      // k byte offset in 64B row

  // fragment ds_read offsets (within slot), swizzled
  int offA[8], offB[4];
  #pragma unroll
  for (int fm=0; fm<8; fm++){ int r = wm*128 + fm*16 + lrow; offA[fm] = r*64 + (lkb ^ (((r>>1)&3)<<4)); }
  #pragma unroll
  for (int fn=0; fn<4; fn++){ int r = wn*64  + fn*16 + lrow; offB[fn] = r*64 + (lkb ^ (((r>>1)&3)<<4)); }

  // staging geometry: unit h covers LDS rows {h*64..h*64+63} per 128-half:
  // wave w writes rows (w&3)*16+(w>>2)*128 + h*64 .. +15  (1KB linear)
  const int Rb0 = (w&3)*16 + (w>>2)*128 + (lane>>2);
  const int Rb1 = Rb0 + 64;
  const int ob  = (lane&3)*16;
  const int sw0 = ((Rb0>>1)&3)<<4, sw1 = ((Rb1>>1)&3)<<4;
  const char* Ag0 = (const char*)xb + (size_t)(m0+Rb0)*2048 + (ob ^ sw0);
  const char* Ag1 = (const char*)xb + (size_t)(m0+Rb1)*2048 + (ob ^ sw1);
  const char* Bg0 = (const char*)Wb + (size_t)(n0+Rb0)*2048 + (ob ^ sw0);
  const char* Bg1 = (const char*)Wb + (size_t)(n0+Rb1)*2048 + (ob ^ sw1);
  const int dH0 = ((w&3)*16 + (w>>2)*128)*64 + lane*16;  // h0 dest in slot
  const int dH1 = dH0 + 4096;                            // +64 rows

  f32x4 acc[8][4];
  #pragma unroll
  for (int a=0;a<8;a++)
    #pragma unroll
    for (int b=0;b<4;b++) acc[a][b] = (f32x4){0.f,0.f,0.f,0.f};

  // prologue: tile0 fully, tile1 h0 units
  GLL(Ag0 +  0, lds + dH0);            GLL(Ag1 +  0, lds + dH1);
  GLL(Bg0 +  0, lds + 32768 + dH0);    GLL(Bg1 +  0, lds + 32768 + dH1);
  GLL(Ag0 + 64, lds + 16384 + dH0);    GLL(Bg0 + 64, lds + 49152 + dH0);

  #pragma unroll 1
  for (int t = 0; t < 32; ++t){
    const int s = t & 1;
    const char* Ab = lds + s*16384;
    const char* Bb = lds + 32768 + s*16384;
    // ---- phase 1 ----
    if (t < 31){
      const int s1 = (t+1)&1;
      GLL(Ag1 + (t+1)*64, lds + s1*16384 + dH1);
      GLL(Bg1 + (t+1)*64, lds + 32768 + s1*16384 + dH1);
      asm volatile("s_waitcnt vmcnt(4)" ::: "memory");
    } else {
      asm volatile("s_waitcnt vmcnt(0)" ::: "memory");
    }
    __builtin_amdgcn_s_barrier();
    short8 bf[4];
    #pragma unroll
    for (int fn=0;fn<4;fn++) bf[fn] = *(const short8*)(Bb + offB[fn]);
    short8 af[4];
    #pragma unroll
    for (int fm=0;fm<4;fm++) af[fm] = *(const short8*)(Ab + offA[fm]);
    __builtin_amdgcn_s_setprio(1);
    #pragma unroll
    for (int fm=0;fm<4;fm++)
      #pragma unroll
      for (int fn=0;fn<4;fn++)
        acc[fm][fn] = __builtin_amdgcn_mfma_f32_16x16x32_bf16(af[fm], bf[fn], acc[fm][fn], 0, 0, 0);
    __builtin_amdgcn_s_setprio(0);
    __builtin_amdgcn_s_barrier();
    // ---- phase 2 ----
    if (t < 30){
      const int s2 = t & 1;   // t+2 shares slot with t
      GLL(Ag0 + (t+2)*64, lds + s2*16384 + dH0);
      GLL(Bg0 + (t+2)*64, lds + 32768 + s2*16384 + dH0);
    }
    short8 ag[4];
    #pragma unroll
    for (int fm=0;fm<4;fm++) ag[fm] = *(const short8*)(Ab + offA[4+fm]);
    __builtin_amdgcn_s_setprio(1);
    #pragma unroll
    for (int fm=0;fm<4;fm++)
      #pragma unroll
      for (int fn=0;fn<4;fn++)
        acc[4+fm][fn] = __builtin_amdgcn_mfma_f32_16x16x32_bf16(ag[fm], bf[fn], acc[4+fm][fn], 0, 0, 0);
    __builtin_amdgcn_s_setprio(0);
    __builtin_amdgcn_s_barrier();
  }

  // ---- LoRA K=32 epilogue step: acc += HG[m] @ BTt[n]^T ----
  {
    const char* Hg0 = (const char*)HG  + (size_t)(m0+Rb0)*64 + (ob ^ sw0);
    const char* Hg1 = (const char*)HG  + (size_t)(m0+Rb1)*64 + (ob ^ sw1);
    const char* Tg0 = (const char*)BTt + (size_t)(n0+Rb0)*64 + (ob ^ sw0);
    const char* Tg1 = (const char*)BTt + (size_t)(n0+Rb1)*64 + (ob ^ sw1);
    GLL(Hg0, lds + dH0);          GLL(Hg1, lds + dH1);
    GLL(Tg0, lds + 32768 + dH0);  GLL(Tg1, lds + 32768 + dH1);
    asm volatile("s_waitcnt vmcnt(0)" ::: "memory");
    __builtin_amdgcn_s_barrier();
    short8 hb[4];
    #pragma unroll
    for (int fn=0;fn<4;fn++) hb[fn] = *(const short8*)(lds + 32768 + offB[fn]);
    #pragma unroll
    for (int fm=0;fm<8;fm++){
      short8 ha = *(const short8*)(lds + offA[fm]);
      #pragma unroll
      for (int fn=0;fn<4;fn++)
        acc[fm][fn] = __builtin_amdgcn_mfma_f32_16x16x32_bf16(ha, hb[fn], acc[fm][fn], 0, 0, 0);
    }
  }

  // ---- store: + bias ----
  #pragma unroll
  for (int fn=0;fn<4;fn++){
    int col = n0 + wn*64 + fn*16 + lrow;
    float bv = bias[col];
    #pragma unroll
    for (int fm=0;fm<8;fm++){
      int rb = m0 + wm*128 + fm*16 + (lane>>4)*4;
      #pragma unroll
      for (int j=0;j<4;j++)
        out[(size_t)(rb+j)*1024 + col] = acc[fm][fn][j] + bv;
    }
  }
}

// ---------------- host ---------------------------------------------------
extern "C" void kernel_launch(void* const* d_in, const int* in_sizes, int n_in,
                              void* d_out, int out_size, void* d_ws, size_t ws_size,
                              hipStream_t stream){
  const float* x  = (const float*)d_in[0];
  const float* W  = (const float*)d_in[1];
  const float* bb = (const float*)d_in[2];
  const float* Wr = (const float*)d_in[3];
  const float* A  = (const float*)d_in[4];
  const float* Bm = (const float*)d_in[5];
  float* out = (float*)d_out;
  char* ws = (char*)d_ws;

  // ws layout (bytes): Wb 2MB | BTt 64KB | W2b 64KB | gate 512KB | HG 1MB | xb 32MB
  unsigned short* Wb   = (unsigned short*)(ws + 0);
  unsigned short* BTt  = (unsigned short*)(ws + 2097152);
  unsigned short* W2b  = (unsigned short*)(ws + 2162688);
  float*          gate = (float*)         (ws + 2228224);
  unsigned short* HG   = (unsigned short*)(ws + 2752512);
  unsigned short* xb   = (unsigned short*)(ws + 3801088);

  kconv<<<4096, 256, 0, stream>>>(W, A, Bm, Wb, BTt, W2b);
  kxl<<<1024, 256, 0, stream>>>(x, Wr, xb, gate);
  kh<<<256, 256, 0, stream>>>(xb, W2b, gate, HG);
  kgemm2<<<256, 512, 0, stream>>>(xb, Wb, BTt, HG, bb, out);
}

// Round 4
// 95.846 us; speedup vs baseline: 4.6093x; 1.0168x over previous
//
#include <hip/hip_runtime.h>
#include <cstdint>

typedef __attribute__((ext_vector_type(8))) short short8;
typedef __attribute__((ext_vector_type(4))) float f32x4;

__device__ inline unsigned short f2bf(float f){
  union { float f; uint32_t u; } v; v.f = f;
  uint32_t r = v.u + 0x7FFFu + ((v.u >> 16) & 1u);
  return (unsigned short)(r >> 16);
}

#define GLL(gp, lp) __builtin_amdgcn_global_load_lds(              \
    (const __attribute__((address_space(1))) void*)(gp),           \
    (__attribute__((address_space(3))) void*)(lp), 16, 0, 0)

// ---------------- kernel 1: weight conversions --------------------------
__global__ __launch_bounds__(256) void kconv(const float* __restrict__ W,
                                             const float* __restrict__ A,
                                             const float* __restrict__ Bm,
                                             unsigned short* __restrict__ Wb,
                                             unsigned short* __restrict__ BTt,
                                             unsigned short* __restrict__ W2b){
  int i = blockIdx.x * 256 + threadIdx.x;
  Wb[i] = f2bf(W[i]);
  if (i < 32768){
    int o = i >> 5, c = i & 31;
    BTt[i] = f2bf(Bm[(size_t)c*1024 + o]);
    int n = i >> 10, d = i & 1023;
    W2b[i] = f2bf(A[(((size_t)(n>>2))*1024 + d)*4 + (n&3)]);
  }
}

// ---------------- kernel 2: x->bf16 + f32 router + gating ---------------
__global__ __launch_bounds__(256) void kxl(const float* __restrict__ x,
                                           const float* __restrict__ Wr,
                                           unsigned short* __restrict__ xb,
                                           float* __restrict__ gate){
  __shared__ float wr[8192];
  const int tid  = threadIdx.x;
  const int lane = tid & 63;
  const int w    = tid >> 6;
  {
    const float4* s  = (const float4*)Wr;
    float4*       d4 = (float4*)wr;
    #pragma unroll
    for (int j=0;j<8;j++) d4[j*256+tid] = s[j*256+tid];
  }
  __syncthreads();
  const float4* wr4 = (const float4*)wr;
  #pragma unroll 1
  for (int tt=0; tt<4; tt++){
    const size_t tok = (size_t)blockIdx.x*16 + w*4 + tt;
    const float4* xr = (const float4*)(x + tok*1024);
    ushort4*      xd = (ushort4*)(xb + tok*1024);
    float4 xv[4];
    #pragma unroll
    for (int c=0;c<4;c++){
      xv[c] = xr[c*64 + lane];
      ushort4 o4; o4.x=f2bf(xv[c].x); o4.y=f2bf(xv[c].y);
      o4.z=f2bf(xv[c].z); o4.w=f2bf(xv[c].w);
      xd[c*64 + lane] = o4;
    }
    float p[8];
    #pragma unroll
    for (int e=0;e<8;e++){
      float a = 0.f;
      #pragma unroll
      for (int c=0;c<4;c++){
        float4 wv = wr4[e*256 + c*64 + lane];
        a += xv[c].x*wv.x + xv[c].y*wv.y + xv[c].z*wv.z + xv[c].w*wv.w;
      }
      p[e] = a;
    }
    #pragma unroll
    for (int off=32; off; off>>=1){
      #pragma unroll
      for (int e=0;e<8;e++) p[e] += __shfl_xor(p[e], off, 64);
    }
    if (lane == 0){
      float mx = p[0];
      #pragma unroll
      for (int e=1;e<8;e++) mx = fmaxf(mx, p[e]);
      float ex[8], s2 = 0.f;
      #pragma unroll
      for (int e=0;e<8;e++){ ex[e] = __expf(p[e]-mx); s2 += ex[e]; }
      int i1 = 0; float v1 = ex[0];
      #pragma unroll
      for (int e=1;e<8;e++) if (ex[e] > v1){ v1 = ex[e]; i1 = e; }
      int i2 = -1; float v2 = -1.f;
      #pragma unroll
      for (int e=0;e<8;e++) if (e != i1 && ex[e] > v2){ v2 = ex[e]; i2 = e; }
      float g1 = v1/s2, g2 = v2/s2;
      float rs = 1.f/(g1 + g2 + 1e-6f);
      float* go = gate + tok*8;
      #pragma unroll
      for (int e=0;e<8;e++) go[e] = (e==i1 ? g1 : (e==i2 ? g2 : 0.f)) * rs;
    }
  }
}

// ---------------- kernel 3: HG = (x @ A) * gate via MFMA ----------------
__global__ __launch_bounds__(256) void kh(const unsigned short* __restrict__ xbp,
                                          const unsigned short* __restrict__ W2b,
                                          const float* __restrict__ gate,
                                          unsigned short* __restrict__ HG){
  const int tid  = threadIdx.x;
  const int lane = tid & 63;
  const int wid  = tid >> 6;
  const int lrow = lane & 15;
  const int lk   = (lane >> 4) * 8;
  const int tok0 = blockIdx.x*64 + wid*16;
  f32x4 acc0 = {0.f,0.f,0.f,0.f}, acc1 = {0.f,0.f,0.f,0.f};
  const unsigned short* b0 = W2b + (size_t)lrow*1024 + lk;
  const unsigned short* b1 = W2b + (size_t)(16+lrow)*1024 + lk;
  const unsigned short* ar = xbp + (size_t)(tok0+lrow)*1024 + lk;
  #pragma unroll 4
  for (int ks=0; ks<32; ks++){
    short8 av  = *(const short8*)(ar + ks*32);
    short8 bv0 = *(const short8*)(b0 + ks*32);
    short8 bv1 = *(const short8*)(b1 + ks*32);
    acc0 = __builtin_amdgcn_mfma_f32_16x16x32_bf16(av, bv0, acc0, 0, 0, 0);
    acc1 = __builtin_amdgcn_mfma_f32_16x16x32_bf16(av, bv1, acc1, 0, 0, 0);
  }
  #pragma unroll
  for (int j=0;j<4;j++){
    int tok = tok0 + (lane>>4)*4 + j;
    float g0 = gate[(size_t)tok*8 + (lrow>>2)];
    float g1 = gate[(size_t)tok*8 + 4 + (lrow>>2)];
    HG[(size_t)tok*32 + lrow]      = f2bf(acc0[j]*g0);
    HG[(size_t)tok*32 + 16 + lrow] = f2bf(acc1[j]*g1);
  }
}

// ---------------- kernel 4: 256x256 8-phase GEMM + LoRA epilogue --------
// BK=64, 128KB LDS dbuf, 8 waves (2Mx4N), 4 phases/K-tile, counted vmcnt(4),
// swizzle byte ^= (row&7)<<4 via pre-swizzled global src + swizzled ds_read.
__global__ __launch_bounds__(512, 2) void kgemm3(const unsigned short* __restrict__ xb,
                                                 const unsigned short* __restrict__ Wb,
                                                 const unsigned short* __restrict__ BTt,
                                                 const unsigned short* __restrict__ HG,
                                                 const float* __restrict__ bias,
                                                 float* __restrict__ out){
  __shared__ char lds[131072];     // A slots @0,@32K ; B slots @64K,@96K
  char* ldsc = lds;
  const int tid  = threadIdx.x;
  const int lane = tid & 63;
  const int w    = tid >> 6;
  const int xcd  = blockIdx.x & 7, jj = blockIdx.x >> 3;
  const int nblk = xcd >> 1;
  const int mblk = (xcd & 1)*32 + jj;
  const int m0 = mblk << 8, n0 = nblk << 8;
  const int wm = w >> 2, wn = w & 3;
  const int lrow = lane & 15;
  const int q    = lane >> 4;

  // ds_read frag offsets (BK=64 slot: [256 rows][128B], swz bits 4-6)
  const int swzk = (lrow & 7) << 4;
  int offA[8], offB[4];
  #pragma unroll
  for (int fm=0; fm<8; fm++){ int r = wm*128 + fm*16 + lrow; offA[fm] = r*128 + ((q<<4) ^ swzk); }
  #pragma unroll
  for (int fn=0; fn<4; fn++){ int r = wn*64  + fn*16 + lrow; offB[fn] = r*128 + ((q<<4) ^ swzk); }

  // staging: per GLL a wave writes 8 rows x 128B (1KB linear LDS)
  const int rowL = lane >> 3;
  const int colb = ((lane & 7) ^ rowL) << 4;
  // A halves follow READ-phase row sets: h0'={0-63,128-191}, h1'=+64
  const int rbA = (w>>2)*128 + (w&3)*16;          // unit i=0 rows; i=1: +8
  const int rbB = w*16;                            // B half h: +h*128
  const char* AgA = (const char*)xb + ((size_t)(m0 + rbA + rowL) << 11) + colb;
  const char* BgA = (const char*)Wb + ((size_t)(n0 + rbB + rowL) << 11) + colb;

#define STG_A(tt, h, ss) do{                                                        \
    GLL(AgA + (size_t)(h)*131072 + (tt)*128,                                        \
        ldsc + (ss)*32768 + (rbA + (h)*64)*128 + lane*16);                          \
    GLL(AgA + (size_t)(h)*131072 + 16384 + (tt)*128,                                \
        ldsc + (ss)*32768 + (rbA + (h)*64 + 8)*128 + lane*16); }while(0)
#define STG_B(tt, h, ss) do{                                                        \
    GLL(BgA + (size_t)(h)*262144 + (tt)*128,                                        \
        ldsc + 65536 + (ss)*32768 + (rbB + (h)*128)*128 + lane*16);                 \
    GLL(BgA + (size_t)(h)*262144 + 16384 + (tt)*128,                                \
        ldsc + 65536 + (ss)*32768 + (rbB + (h)*128 + 8)*128 + lane*16); }while(0)

  f32x4 acc[8][4];
  #pragma unroll
  for (int a=0;a<8;a++)
    #pragma unroll
    for (int b=0;b<4;b++) acc[a][b] = (f32x4){0.f,0.f,0.f,0.f};

  // prologue: tile0 full + tile1 A halves
  STG_A(0,0,0); STG_A(0,1,0); STG_B(0,0,0); STG_B(0,1,0);
  STG_A(1,0,1); STG_A(1,1,1);
  asm volatile("s_waitcnt vmcnt(4)" ::: "memory");
  __builtin_amdgcn_s_barrier();

  #pragma unroll 1
  for (int t = 0; t < 16; ++t){
    const int s = t & 1, sn = s ^ 1;
    const char* Ab = ldsc + s*32768;
    const char* Bb = ldsc + 65536 + s*32768;
    short8 a[8], b0[4], b1[4];
    // ---- ph0: read A(qm0)+B(qn0); stage (t+1)B h0 ----
    #pragma unroll
    for (int fm=0; fm<4; fm++){
      a[fm*2]   = *(const short8*)(Ab + offA[fm]);
      a[fm*2+1] = *(const short8*)(Ab + (offA[fm]^64));
    }
    #pragma unroll
    for (int fn=0; fn<2; fn++){
      b0[fn*2]   = *(const short8*)(Bb + offB[fn]);
      b0[fn*2+1] = *(const short8*)(Bb + (offB[fn]^64));
    }
    if (t < 15) STG_B(t+1, 0, sn);
    __builtin_amdgcn_s_barrier();
    __builtin_amdgcn_s_setprio(1);
    #pragma unroll
    for (int kk=0;kk<2;kk++)
      #pragma unroll
      for (int fm=0;fm<4;fm++)
        #pragma unroll
        for (int fn=0;fn<2;fn++)
          acc[fm][fn] = __builtin_amdgcn_mfma_f32_16x16x32_bf16(a[fm*2+kk], b0[fn*2+kk], acc[fm][fn], 0, 0, 0);
    __builtin_amdgcn_s_setprio(0);
    __builtin_amdgcn_s_barrier();
    // ---- ph1: read B(qn1); stage (t+1)B h1 ----
    #pragma unroll
    for (int fn=0; fn<2; fn++){
      b1[fn*2]   = *(const short8*)(Bb + offB[2+fn]);
      b1[fn*2+1] = *(const short8*)(Bb + (offB[2+fn]^64));
    }
    if (t < 15) STG_B(t+1, 1, sn);
    __builtin_amdgcn_s_barrier();
    __builtin_amdgcn_s_setprio(1);
    #pragma unroll
    for (int kk=0;kk<2;kk++)
      #pragma unroll
      for (int fm=0;fm<4;fm++)
        #pragma unroll
        for (int fn=0;fn<2;fn++)
          acc[fm][2+fn] = __builtin_amdgcn_mfma_f32_16x16x32_bf16(a[fm*2+kk], b1[fn*2+kk], acc[fm][2+fn], 0, 0, 0);
    __builtin_amdgcn_s_setprio(0);
    __builtin_amdgcn_s_barrier();
    // ---- ph2: read A(qm1); stage (t+2)A h0' ----
    #pragma unroll
    for (int fm=0; fm<4; fm++){
      a[fm*2]   = *(const short8*)(Ab + offA[4+fm]);
      a[fm*2+1] = *(const short8*)(Ab + (offA[4+fm]^64));
    }
    if (t < 14) STG_A(t+2, 0, s);
    __builtin_amdgcn_s_barrier();
    __builtin_amdgcn_s_setprio(1);
    #pragma unroll
    for (int kk=0;kk<2;kk++)
      #pragma unroll
      for (int fm=0;fm<4;fm++)
        #pragma unroll
        for (int fn=0;fn<2;fn++)
          acc[4+fm][2+fn] = __builtin_amdgcn_mfma_f32_16x16x32_bf16(a[fm*2+kk], b1[fn*2+kk], acc[4+fm][2+fn], 0, 0, 0);
    __builtin_amdgcn_s_setprio(0);
    __builtin_amdgcn_s_barrier();
    // ---- ph3: stage (t+2)A h1'; tile-boundary counted vmcnt ----
    if (t < 14){
      STG_A(t+2, 1, s);
      asm volatile("s_waitcnt vmcnt(4)" ::: "memory");
    } else {
      asm volatile("s_waitcnt vmcnt(0)" ::: "memory");
    }
    __builtin_amdgcn_s_barrier();
    __builtin_amdgcn_s_setprio(1);
    #pragma unroll
    for (int kk=0;kk<2;kk++)
      #pragma unroll
      for (int fm=0;fm<4;fm++)
        #pragma unroll
        for (int fn=0;fn<2;fn++)
          acc[4+fm][fn] = __builtin_amdgcn_mfma_f32_16x16x32_bf16(a[fm*2+kk], b0[fn*2+kk], acc[4+fm][fn], 0, 0, 0);
    __builtin_amdgcn_s_setprio(0);
    __builtin_amdgcn_s_barrier();
  }

  // ---- LoRA K=32 step (64B rows, swz bits 4-5 by (r>>1)&3) ----
  {
    const int colb2 = (((lane & 3) ^ ((lane >> 3) & 3)) << 4);
    const char* Hg = (const char*)HG  + (size_t)(m0 + w*32 + (lane>>2))*64 + colb2;
    const char* Tg = (const char*)BTt + (size_t)(n0 + w*32 + (lane>>2))*64 + colb2;
    const int dst2 = w*2048 + lane*16;
    GLL(Hg,        ldsc + dst2);
    GLL(Hg + 1024, ldsc + dst2 + 1024);
    GLL(Tg,        ldsc + 65536 + dst2);
    GLL(Tg + 1024, ldsc + 65536 + dst2 + 1024);
    asm volatile("s_waitcnt vmcnt(0)" ::: "memory");
    __builtin_amdgcn_s_barrier();
    const int swz2 = ((lrow >> 1) & 3) << 4;
    short8 hb[4];
    #pragma unroll
    for (int fn=0; fn<4; fn++){
      int r = wn*64 + fn*16 + lrow;
      hb[fn] = *(const short8*)(ldsc + 65536 + r*64 + ((q<<4) ^ swz2));
    }
    #pragma unroll
    for (int fm=0; fm<8; fm++){
      int r = wm*128 + fm*16 + lrow;
      short8 ha = *(const short8*)(ldsc + r*64 + ((q<<4) ^ swz2));
      #pragma unroll
      for (int fn=0; fn<4; fn++)
        acc[fm][fn] = __builtin_amdgcn_mfma_f32_16x16x32_bf16(ha, hb[fn], acc[fm][fn], 0, 0, 0);
    }
  }

  // ---- store: + bias ----
  #pragma unroll
  for (int fn=0;fn<4;fn++){
    int col = n0 + wn*64 + fn*16 + lrow;
    float bv = bias[col];
    #pragma unroll
    for (int fm=0;fm<8;fm++){
      int rb = m0 + wm*128 + fm*16 + q*4;
      #pragma unroll
      for (int j=0;j<4;j++)
        out[(size_t)(rb+j)*1024 + col] = acc[fm][fn][j] + bv;
    }
  }
#undef STG_A
#undef STG_B
}

// ---------------- host ---------------------------------------------------
extern "C" void kernel_launch(void* const* d_in, const int* in_sizes, int n_in,
                              void* d_out, int out_size, void* d_ws, size_t ws_size,
                              hipStream_t stream){
  const float* x  = (const float*)d_in[0];
  const float* W  = (const float*)d_in[1];
  const float* bb = (const float*)d_in[2];
  const float* Wr = (const float*)d_in[3];
  const float* A  = (const float*)d_in[4];
  const float* Bm = (const float*)d_in[5];
  float* out = (float*)d_out;
  char* ws = (char*)d_ws;

  unsigned short* Wb   = (unsigned short*)(ws + 0);
  unsigned short* BTt  = (unsigned short*)(ws + 2097152);
  unsigned short* W2b  = (unsigned short*)(ws + 2162688);
  float*          gate = (float*)         (ws + 2228224);
  unsigned short* HG   = (unsigned short*)(ws + 2752512);
  unsigned short* xb   = (unsigned short*)(ws + 3801088);

  kconv<<<4096, 256, 0, stream>>>(W, A, Bm, Wb, BTt, W2b);
  kxl<<<1024, 256, 0, stream>>>(x, Wr, xb, gate);
  kh<<<256, 256, 0, stream>>>(xb, W2b, gate, HG);
  kgemm3<<<256, 512, 0, stream>>>(xb, Wb, BTt, HG, bb, out);
}

// Round 5
// 91.209 us; speedup vs baseline: 4.8437x; 1.0508x over previous
//
#include <hip/hip_runtime.h>
#include <cstdint>

typedef __attribute__((ext_vector_type(8))) short short8;
typedef __attribute__((ext_vector_type(4))) float f32x4;

__device__ inline unsigned short f2bf(float f){
  union { float f; uint32_t u; } v; v.f = f;
  uint32_t r = v.u + 0x7FFFu + ((v.u >> 16) & 1u);
  return (unsigned short)(r >> 16);
}

#define GLL(gp, lp) __builtin_amdgcn_global_load_lds(              \
    (const __attribute__((address_space(1))) void*)(gp),           \
    (__attribute__((address_space(3))) void*)(lp), 16, 0, 0)

// inline-asm LDS read: invisible to the compiler's waitcnt-insertion pass,
// so our counted vmcnt/lgkmcnt survive (rule #18: pair with sched_barrier).
#define DSR(dst, addr) asm volatile("ds_read_b128 %0, %1" : "=v"(dst) : "v"(addr))

// ---------------- kernel 1: weight conversions --------------------------
__global__ __launch_bounds__(256) void kconv(const float* __restrict__ W,
                                             const float* __restrict__ A,
                                             const float* __restrict__ Bm,
                                             unsigned short* __restrict__ Wb,
                                             unsigned short* __restrict__ BTt,
                                             unsigned short* __restrict__ W2b){
  int i = blockIdx.x * 256 + threadIdx.x;
  Wb[i] = f2bf(W[i]);
  if (i < 32768){
    int o = i >> 5, c = i & 31;
    BTt[i] = f2bf(Bm[(size_t)c*1024 + o]);
    int n = i >> 10, d = i & 1023;
    W2b[i] = f2bf(A[(((size_t)(n>>2))*1024 + d)*4 + (n&3)]);
  }
}

// ---------------- kernel 2: x->bf16 + f32 router + gating ---------------
// 8 tokens per wave in parallel: lane = (tok=lane>>3, ln8=lane&7).
// Coalesced 128B/row-group loads, 3-level shfl reduce, 8 parallel softmaxes.
__global__ __launch_bounds__(256) void kxl2(const float* __restrict__ x,
                                            const float* __restrict__ Wr,
                                            unsigned short* __restrict__ xb,
                                            float* __restrict__ gate){
  __shared__ float wr[8192];
  const int tid  = threadIdx.x;
  const int lane = tid & 63;
  const int wid  = tid >> 6;
  {
    const float4* s  = (const float4*)Wr;
    float4*       d4 = (float4*)wr;
    #pragma unroll
    for (int j=0;j<8;j++) d4[j*256+tid] = s[j*256+tid];
  }
  __syncthreads();
  const int tk  = lane >> 3, ln8 = lane & 7;
  const size_t tok = (size_t)blockIdx.x*32 + wid*8 + tk;
  const float4* xr = (const float4*)(x + tok*1024);
  ushort4*      xd = (ushort4*)(xb + tok*1024);
  const float4* wv = (const float4*)wr;
  float p[8] = {0.f,0.f,0.f,0.f,0.f,0.f,0.f,0.f};
  #pragma unroll 4
  for (int it=0; it<32; it++){
    float4 v = xr[it*8 + ln8];
    ushort4 o; o.x=f2bf(v.x); o.y=f2bf(v.y); o.z=f2bf(v.z); o.w=f2bf(v.w);
    xd[it*8 + ln8] = o;
    #pragma unroll
    for (int e=0;e<8;e++){
      float4 wq = wv[e*256 + it*8 + ln8];
      p[e] += v.x*wq.x + v.y*wq.y + v.z*wq.z + v.w*wq.w;
    }
  }
  #pragma unroll
  for (int off=1; off<8; off<<=1){
    #pragma unroll
    for (int e=0;e<8;e++) p[e] += __shfl_xor(p[e], off, 64);
  }
  if (ln8 == 0){
    float mx = p[0];
    #pragma unroll
    for (int e=1;e<8;e++) mx = fmaxf(mx, p[e]);
    float ex[8], s2 = 0.f;
    #pragma unroll
    for (int e=0;e<8;e++){ ex[e] = __expf(p[e]-mx); s2 += ex[e]; }
    int i1 = 0; float v1 = ex[0];
    #pragma unroll
    for (int e=1;e<8;e++) if (ex[e] > v1){ v1 = ex[e]; i1 = e; }
    int i2 = -1; float v2 = -1.f;
    #pragma unroll
    for (int e=0;e<8;e++) if (e != i1 && ex[e] > v2){ v2 = ex[e]; i2 = e; }
    float g1 = v1/s2, g2 = v2/s2;
    float rs = 1.f/(g1 + g2 + 1e-6f);
    float* go = gate + tok*8;
    #pragma unroll
    for (int e=0;e<8;e++) go[e] = (e==i1 ? g1 : (e==i2 ? g2 : 0.f)) * rs;
  }
}

// ---------------- kernel 3: HG = (x @ A) * gate via MFMA ----------------
__global__ __launch_bounds__(256) void kh(const unsigned short* __restrict__ xbp,
                                          const unsigned short* __restrict__ W2b,
                                          const float* __restrict__ gate,
                                          unsigned short* __restrict__ HG){
  const int tid  = threadIdx.x;
  const int lane = tid & 63;
  const int wid  = tid >> 6;
  const int lrow = lane & 15;
  const int lk   = (lane >> 4) * 8;
  const int tok0 = blockIdx.x*64 + wid*16;
  f32x4 acc0 = {0.f,0.f,0.f,0.f}, acc1 = {0.f,0.f,0.f,0.f};
  const unsigned short* b0 = W2b + (size_t)lrow*1024 + lk;
  const unsigned short* b1 = W2b + (size_t)(16+lrow)*1024 + lk;
  const unsigned short* ar = xbp + (size_t)(tok0+lrow)*1024 + lk;
  #pragma unroll 4
  for (int ks=0; ks<32; ks++){
    short8 av  = *(const short8*)(ar + ks*32);
    short8 bv0 = *(const short8*)(b0 + ks*32);
    short8 bv1 = *(const short8*)(b1 + ks*32);
    acc0 = __builtin_amdgcn_mfma_f32_16x16x32_bf16(av, bv0, acc0, 0, 0, 0);
    acc1 = __builtin_amdgcn_mfma_f32_16x16x32_bf16(av, bv1, acc1, 0, 0, 0);
  }
  #pragma unroll
  for (int j=0;j<4;j++){
    int tok = tok0 + (lane>>4)*4 + j;
    float g0 = gate[(size_t)tok*8 + (lrow>>2)];
    float g1 = gate[(size_t)tok*8 + 4 + (lrow>>2)];
    HG[(size_t)tok*32 + lrow]      = f2bf(acc0[j]*g0);
    HG[(size_t)tok*32 + 16 + lrow] = f2bf(acc1[j]*g1);
  }
}

// ---------------- kernel 4: 256x256 GEMM, asm ds_read + counted waits ---
// BK=64, 128KB dbuf, 8 waves (2Mx4N), 4 phases/tile {asm ds_read; 2xGLL;
// [vmcnt]; barrier; lgkmcnt(0); sched_barrier; 16 MFMA; barrier}.
// vmcnt(2) only at end of ph0 and ph3 (FIFO-traced). Swizzle ^(row&7)<<4.
__global__ __launch_bounds__(512, 2) void kgemm5(const unsigned short* __restrict__ xb,
                                                 const unsigned short* __restrict__ Wb,
                                                 const unsigned short* __restrict__ BTt,
                                                 const unsigned short* __restrict__ HG,
                                                 const float* __restrict__ bias,
                                                 float* __restrict__ out){
  __shared__ __attribute__((aligned(128))) char lds[131072]; // A@0/32K, B@64K/96K
  char* ldsc = lds;
  const uint32_t L = (uint32_t)(uintptr_t)lds;
  const int tid  = threadIdx.x;
  const int lane = tid & 63;
  const int w    = tid >> 6;
  const int xcd  = blockIdx.x & 7, jj = blockIdx.x >> 3;
  const int nblk = xcd >> 1;
  const int mblk = (xcd & 1)*32 + jj;
  const int m0 = mblk << 8, n0 = nblk << 8;
  const int wm = w >> 2, wn = w & 3;
  const int lrow = lane & 15;
  const int q    = lane >> 4;

  // frag offsets within a slot ([256 rows][128B], swizzle bits 4-6)
  const int swzk = (lrow & 7) << 4;
  uint32_t offA[8], offB[4];
  #pragma unroll
  for (int fm=0; fm<8; fm++){ int r = wm*128 + fm*16 + lrow; offA[fm] = r*128 + ((q<<4) ^ swzk); }
  #pragma unroll
  for (int fn=0; fn<4; fn++){ int r = wn*64  + fn*16 + lrow; offB[fn] = r*128 + ((q<<4) ^ swzk); }

  // staging: per GLL one wave writes 8 rows x 128B, row-linear dest,
  // inverse-swizzled global source.  A halves = read-phase sets
  // h0'={0-63,128-191}; B halves h0''={0-31,64-95,128-159,192-223}.
  const int rowL = lane >> 3;
  const int colb = ((lane & 7) ^ rowL) << 4;
  const int rbA = (w>>2)*128 + (w&3)*16;
  const int rbB = (w>>1)*64 + (w&1)*16;
  const char* Ag = (const char*)xb + ((size_t)(m0 + rbA + rowL) << 11) + colb;
  const char* Bg = (const char*)Wb + ((size_t)(n0 + rbB + rowL) << 11) + colb;

#define STG_A(tt, h, ss) do{                                                    \
    GLL(Ag + (size_t)(h)*131072 + (tt)*128,                                     \
        ldsc + (ss)*32768 + (rbA + (h)*64)*128 + lane*16);                      \
    GLL(Ag + (size_t)(h)*131072 + 16384 + (tt)*128,                             \
        ldsc + (ss)*32768 + (rbA + (h)*64 + 8)*128 + lane*16); }while(0)
#define STG_B(tt, h, ss) do{                                                    \
    GLL(Bg + (size_t)(h)*65536 + (tt)*128,                                      \
        ldsc + 65536 + (ss)*32768 + (rbB + (h)*32)*128 + lane*16);              \
    GLL(Bg + (size_t)(h)*65536 + 16384 + (tt)*128,                              \
        ldsc + 65536 + (ss)*32768 + (rbB + (h)*32 + 8)*128 + lane*16); }while(0)

  f32x4 acc[8][4];
  #pragma unroll
  for (int a2=0;a2<8;a2++)
    #pragma unroll
    for (int b2=0;b2<4;b2++) acc[a2][b2] = (f32x4){0.f,0.f,0.f,0.f};

  // prologue: tile0 fully
  STG_A(0,0,0); STG_A(0,1,0); STG_B(0,0,0); STG_B(0,1,0);
  asm volatile("s_waitcnt vmcnt(0)" ::: "memory");
  __builtin_amdgcn_s_barrier();

  short8 a[8], b0[4], b1[4];
  #pragma unroll 1
  for (int t = 0; t < 16; ++t){
    const int s = t & 1, sn = s ^ 1;
    const uint32_t bA = L + s*32768;
    const uint32_t bB = L + 65536 + s*32768;
    // ---- ph0: read A fm0-3 + B fn0-1; stage A(t+1)h0; vmcnt(2) ----
    #pragma unroll
    for (int fm=0; fm<4; fm++){ DSR(a[fm*2], bA+offA[fm]); DSR(a[fm*2+1], bA+(offA[fm]^64u)); }
    #pragma unroll
    for (int fn=0; fn<2; fn++){ DSR(b0[fn*2], bB+offB[fn]); DSR(b0[fn*2+1], bB+(offB[fn]^64u)); }
    if (t < 15){ STG_A(t+1, 0, sn); asm volatile("s_waitcnt vmcnt(2)" ::: "memory"); }
    else       {                    asm volatile("s_waitcnt vmcnt(0)" ::: "memory"); }
    __builtin_amdgcn_s_barrier();
    asm volatile("s_waitcnt lgkmcnt(0)" ::: "memory");
    __builtin_amdgcn_sched_barrier(0);
    __builtin_amdgcn_s_setprio(1);
    #pragma unroll
    for (int kk=0;kk<2;kk++)
      #pragma unroll
      for (int fm=0;fm<4;fm++)
        #pragma unroll
        for (int fn=0;fn<2;fn++)
          acc[fm][fn] = __builtin_amdgcn_mfma_f32_16x16x32_bf16(a[fm*2+kk], b0[fn*2+kk], acc[fm][fn], 0, 0, 0);
    __builtin_amdgcn_s_setprio(0);
    __builtin_amdgcn_s_barrier();
    // ---- ph1: read B fn2-3; stage A(t+1)h1 ----
    #pragma unroll
    for (int fn=0; fn<2; fn++){ DSR(b1[fn*2], bB+offB[2+fn]); DSR(b1[fn*2+1], bB+(offB[2+fn]^64u)); }
    if (t < 15) STG_A(t+1, 1, sn);
    __builtin_amdgcn_s_barrier();
    asm volatile("s_waitcnt lgkmcnt(0)" ::: "memory");
    __builtin_amdgcn_sched_barrier(0);
    __builtin_amdgcn_s_setprio(1);
    #pragma unroll
    for (int kk=0;kk<2;kk++)
      #pragma unroll
      for (int fm=0;fm<4;fm++)
        #pragma unroll
        for (int fn=0;fn<2;fn++)
          acc[fm][2+fn] = __builtin_amdgcn_mfma_f32_16x16x32_bf16(a[fm*2+kk], b1[fn*2+kk], acc[fm][2+fn], 0, 0, 0);
    __builtin_amdgcn_s_setprio(0);
    __builtin_amdgcn_s_barrier();
    // ---- ph2: read A fm4-7; stage B(t+1)h0 ----
    #pragma unroll
    for (int fm=0; fm<4; fm++){ DSR(a[fm*2], bA+offA[4+fm]); DSR(a[fm*2+1], bA+(offA[4+fm]^64u)); }
    if (t < 15) STG_B(t+1, 0, sn);
    __builtin_amdgcn_s_barrier();
    asm volatile("s_waitcnt lgkmcnt(0)" ::: "memory");
    __builtin_amdgcn_sched_barrier(0);
    __builtin_amdgcn_s_setprio(1);
    #pragma unroll
    for (int kk=0;kk<2;kk++)
      #pragma unroll
      for (int fm=0;fm<4;fm++)
        #pragma unroll
        for (int fn=0;fn<2;fn++)
          acc[4+fm][2+fn] = __builtin_amdgcn_mfma_f32_16x16x32_bf16(a[fm*2+kk], b1[fn*2+kk], acc[4+fm][2+fn], 0, 0, 0);
    __builtin_amdgcn_s_setprio(0);
    __builtin_amdgcn_s_barrier();
    // ---- ph3: stage B(t+1)h1; vmcnt(2) ----
    if (t < 15){ STG_B(t+1, 1, sn); asm volatile("s_waitcnt vmcnt(2)" ::: "memory"); }
    __builtin_amdgcn_s_barrier();
    __builtin_amdgcn_s_setprio(1);
    #pragma unroll
    for (int kk=0;kk<2;kk++)
      #pragma unroll
      for (int fm=0;fm<4;fm++)
        #pragma unroll
        for (int fn=0;fn<2;fn++)
          acc[4+fm][fn] = __builtin_amdgcn_mfma_f32_16x16x32_bf16(a[fm*2+kk], b0[fn*2+kk], acc[4+fm][fn], 0, 0, 0);
    __builtin_amdgcn_s_setprio(0);
    __builtin_amdgcn_s_barrier();
  }

  // ---- LoRA K=32 step (64B rows, swz bits 4-5 by (r>>1)&3) ----
  {
    const int colb2 = (((lane & 3) ^ ((lane >> 3) & 3)) << 4);
    const char* Hg = (const char*)HG  + (size_t)(m0 + w*32 + (lane>>2))*64 + colb2;
    const char* Tg = (const char*)BTt + (size_t)(n0 + w*32 + (lane>>2))*64 + colb2;
    const int dst2 = w*2048 + lane*16;
    GLL(Hg,        ldsc + dst2);
    GLL(Hg + 1024, ldsc + dst2 + 1024);
    GLL(Tg,        ldsc + 65536 + dst2);
    GLL(Tg + 1024, ldsc + 65536 + dst2 + 1024);
    asm volatile("s_waitcnt vmcnt(0)" ::: "memory");
    __builtin_amdgcn_s_barrier();
    const int swz2 = ((lrow >> 1) & 3) << 4;
    short8 hb[4];
    #pragma unroll
    for (int fn=0; fn<4; fn++){
      int r = wn*64 + fn*16 + lrow;
      hb[fn] = *(const short8*)(ldsc + 65536 + r*64 + ((q<<4) ^ swz2));
    }
    #pragma unroll
    for (int fm=0; fm<8; fm++){
      int r = wm*128 + fm*16 + lrow;
      short8 ha = *(const short8*)(ldsc + r*64 + ((q<<4) ^ swz2));
      #pragma unroll
      for (int fn=0; fn<4; fn++)
        acc[fm][fn] = __builtin_amdgcn_mfma_f32_16x16x32_bf16(ha, hb[fn], acc[fm][fn], 0, 0, 0);
    }
  }

  // ---- store: + bias ----
  #pragma unroll
  for (int fn=0;fn<4;fn++){
    int col = n0 + wn*64 + fn*16 + lrow;
    float bv = bias[col];
    #pragma unroll
    for (int fm=0;fm<8;fm++){
      int rb = m0 + wm*128 + fm*16 + q*4;
      #pragma unroll
      for (int j=0;j<4;j++)
        out[(size_t)(rb+j)*1024 + col] = acc[fm][fn][j] + bv;
    }
  }
#undef STG_A
#undef STG_B
}

// ---------------- host ---------------------------------------------------
extern "C" void kernel_launch(void* const* d_in, const int* in_sizes, int n_in,
                              void* d_out, int out_size, void* d_ws, size_t ws_size,
                              hipStream_t stream){
  const float* x  = (const float*)d_in[0];
  const float* W  = (const float*)d_in[1];
  const float* bb = (const float*)d_in[2];
  const float* Wr = (const float*)d_in[3];
  const float* A  = (const float*)d_in[4];
  const float* Bm = (const float*)d_in[5];
  float* out = (float*)d_out;
  char* ws = (char*)d_ws;

  unsigned short* Wb   = (unsigned short*)(ws + 0);
  unsigned short* BTt  = (unsigned short*)(ws + 2097152);
  unsigned short* W2b  = (unsigned short*)(ws + 2162688);
  float*          gate = (float*)         (ws + 2228224);
  unsigned short* HG   = (unsigned short*)(ws + 2752512);
  unsigned short* xb   = (unsigned short*)(ws + 3801088);

  kconv<<<4096, 256, 0, stream>>>(W, A, Bm, Wb, BTt, W2b);
  kxl2<<<512, 256, 0, stream>>>(x, Wr, xb, gate);
  kh<<<256, 256, 0, stream>>>(xb, W2b, gate, HG);
  kgemm5<<<256, 512, 0, stream>>>(xb, Wb, BTt, HG, bb, out);
}

// Round 6
// 86.851 us; speedup vs baseline: 5.0867x; 1.0502x over previous
//
#include <hip/hip_runtime.h>
#include <cstdint>

typedef __attribute__((ext_vector_type(8))) short short8;
typedef __attribute__((ext_vector_type(4))) float f32x4;

__device__ inline unsigned short f2bf(float f){
  union { float f; uint32_t u; } v; v.f = f;
  uint32_t r = v.u + 0x7FFFu + ((v.u >> 16) & 1u);
  return (unsigned short)(r >> 16);
}

#define GLL(gp, lp) __builtin_amdgcn_global_load_lds(              \
    (const __attribute__((address_space(1))) void*)(gp),           \
    (__attribute__((address_space(3))) void*)(lp), 16, 0, 0)

// inline-asm LDS read with literal offset (keeps address regs to 4 bases)
#define DSRO(dst, addr, off) \
  asm volatile("ds_read_b128 %0, %1 offset:" off : "=v"(dst) : "v"(addr))

// ---------------- kernel 1: weight conversions --------------------------
__global__ __launch_bounds__(256) void kconv(const float* __restrict__ W,
                                             const float* __restrict__ A,
                                             const float* __restrict__ Bm,
                                             unsigned short* __restrict__ Wb,
                                             unsigned short* __restrict__ BTt,
                                             unsigned short* __restrict__ W2b){
  int i = blockIdx.x * 256 + threadIdx.x;
  Wb[i] = f2bf(W[i]);
  if (i < 32768){
    int o = i >> 5, c = i & 31;
    BTt[i] = f2bf(Bm[(size_t)c*1024 + o]);
    int n = i >> 10, d = i & 1023;
    W2b[i] = f2bf(A[(((size_t)(n>>2))*1024 + d)*4 + (n&3)]);
  }
}

// ---------------- kernel 2: x->bf16 + f32 router + gating ---------------
__global__ __launch_bounds__(256) void kxl2(const float* __restrict__ x,
                                            const float* __restrict__ Wr,
                                            unsigned short* __restrict__ xb,
                                            float* __restrict__ gate){
  __shared__ float wr[8192];
  const int tid  = threadIdx.x;
  const int lane = tid & 63;
  const int wid  = tid >> 6;
  {
    const float4* s  = (const float4*)Wr;
    float4*       d4 = (float4*)wr;
    #pragma unroll
    for (int j=0;j<8;j++) d4[j*256+tid] = s[j*256+tid];
  }
  __syncthreads();
  const int tk  = lane >> 3, ln8 = lane & 7;
  const size_t tok = (size_t)blockIdx.x*32 + wid*8 + tk;
  const float4* xr = (const float4*)(x + tok*1024);
  ushort4*      xd = (ushort4*)(xb + tok*1024);
  const float4* wv = (const float4*)wr;
  float p[8] = {0.f,0.f,0.f,0.f,0.f,0.f,0.f,0.f};
  #pragma unroll 4
  for (int it=0; it<32; it++){
    float4 v = xr[it*8 + ln8];
    ushort4 o; o.x=f2bf(v.x); o.y=f2bf(v.y); o.z=f2bf(v.z); o.w=f2bf(v.w);
    xd[it*8 + ln8] = o;
    #pragma unroll
    for (int e=0;e<8;e++){
      float4 wq = wv[e*256 + it*8 + ln8];
      p[e] += v.x*wq.x + v.y*wq.y + v.z*wq.z + v.w*wq.w;
    }
  }
  #pragma unroll
  for (int off=1; off<8; off<<=1){
    #pragma unroll
    for (int e=0;e<8;e++) p[e] += __shfl_xor(p[e], off, 64);
  }
  if (ln8 == 0){
    float mx = p[0];
    #pragma unroll
    for (int e=1;e<8;e++) mx = fmaxf(mx, p[e]);
    float ex[8], s2 = 0.f;
    #pragma unroll
    for (int e=0;e<8;e++){ ex[e] = __expf(p[e]-mx); s2 += ex[e]; }
    int i1 = 0; float v1 = ex[0];
    #pragma unroll
    for (int e=1;e<8;e++) if (ex[e] > v1){ v1 = ex[e]; i1 = e; }
    int i2 = -1; float v2 = -1.f;
    #pragma unroll
    for (int e=0;e<8;e++) if (e != i1 && ex[e] > v2){ v2 = ex[e]; i2 = e; }
    float g1 = v1/s2, g2 = v2/s2;
    float rs = 1.f/(g1 + g2 + 1e-6f);
    float* go = gate + tok*8;
    #pragma unroll
    for (int e=0;e<8;e++) go[e] = (e==i1 ? g1 : (e==i2 ? g2 : 0.f)) * rs;
  }
}

// ---------------- kernel 3: fused 256x256 GEMM + h-MFMA + LoRA ----------
// Main loop as r5 (asm ds_read, counted vmcnt). Adds: in-loop h = xb@A
// (reuses live a[] frags; W2b frags direct from L2), post-loop gate->HG
// in LDS, LoRA MFMA from LDS. Dispatch remap: same-mblk blocks -> same XCD.
__global__ __launch_bounds__(512, 2) void kgemm6(const unsigned short* __restrict__ xb,
                                                 const unsigned short* __restrict__ Wb,
                                                 const unsigned short* __restrict__ BTt,
                                                 const unsigned short* __restrict__ W2b,
                                                 const float* __restrict__ gate,
                                                 const float* __restrict__ bias,
                                                 float* __restrict__ out){
  __shared__ __attribute__((aligned(128))) char lds[131072]; // A@0/32K, B@64K/96K
  char* ldsc = lds;
  const uint32_t L = (uint32_t)(uintptr_t)lds;
  const int tid  = threadIdx.x;
  const int lane = tid & 63;
  const int w    = tid >> 6;
  // same-XCD A-panel sharing: blocks with equal mblk differ by 64 => same bid%8
  const int mblk = blockIdx.x & 63;
  const int nblk = blockIdx.x >> 6;
  const int m0 = mblk << 8, n0 = nblk << 8;
  const int wm = w >> 2, wn = w & 3;
  const int lrow = lane & 15;
  const int q    = lane >> 4;

  // ds_read base addresses (slot-relative added per tile); swizzle bits 4-6
  const int swzk = (lrow & 7) << 4;
  const uint32_t vA0 = L + (uint32_t)(wm*128 + lrow)*128 + (uint32_t)((q<<4) ^ swzk);
  const uint32_t vA1 = L + (uint32_t)(wm*128 + lrow)*128 + (uint32_t)(((q^4)<<4) ^ swzk);
  const uint32_t vB0 = L + 65536u + (uint32_t)(wn*64 + lrow)*128 + (uint32_t)((q<<4) ^ swzk);
  const uint32_t vB1 = L + 65536u + (uint32_t)(wn*64 + lrow)*128 + (uint32_t)(((q^4)<<4) ^ swzk);

  // staging (linear LDS dest, inverse-swizzled global source)
  const int rowL = lane >> 3;
  const int colb = ((lane & 7) ^ rowL) << 4;
  const int rbA = (w>>2)*128 + (w&3)*16;
  const int rbB = (w>>1)*64 + (w&1)*16;
  const char* Ag = (const char*)xb + ((size_t)(m0 + rbA + rowL) << 11) + colb;
  const char* Bg = (const char*)Wb + ((size_t)(n0 + rbB + rowL) << 11) + colb;

#define STG_A(tt, h, ss) do{                                                    \
    GLL(Ag + (size_t)(h)*131072 + (tt)*128,                                     \
        ldsc + (ss)*32768 + (rbA + (h)*64)*128 + lane*16);                      \
    GLL(Ag + (size_t)(h)*131072 + 16384 + (tt)*128,                             \
        ldsc + (ss)*32768 + (rbA + (h)*64 + 8)*128 + lane*16); }while(0)
#define STG_B(tt, h, ss) do{                                                    \
    GLL(Bg + (size_t)(h)*65536 + (tt)*128,                                      \
        ldsc + 65536 + (ss)*32768 + (rbB + (h)*32)*128 + lane*16);              \
    GLL(Bg + (size_t)(h)*65536 + 16384 + (tt)*128,                              \
        ldsc + 65536 + (ss)*32768 + (rbB + (h)*32 + 8)*128 + lane*16); }while(0)

  f32x4 acc[8][4];
  #pragma unroll
  for (int a2=0;a2<8;a2++)
    #pragma unroll
    for (int b2=0;b2<4;b2++) acc[a2][b2] = (f32x4){0.f,0.f,0.f,0.f};
  f32x4 acc_h[4];
  #pragma unroll
  for (int f=0; f<4; f++) acc_h[f] = (f32x4){0.f,0.f,0.f,0.f};

  // W2b frag pointer: h cols (wn&1)*16 + lrow
  const unsigned short* c2p = W2b + (size_t)((wn&1)*16 + lrow)*1024 + q*8;

  // prologue: tile0 fully
  STG_A(0,0,0); STG_A(0,1,0); STG_B(0,0,0); STG_B(0,1,0);
  asm volatile("s_waitcnt vmcnt(0)" ::: "memory");
  __builtin_amdgcn_s_barrier();

  short8 a[8], b0[4], b1[4];
  #pragma unroll 1
  for (int t = 0; t < 16; ++t){
    const int s = t & 1, sn = s ^ 1;
    const uint32_t va0 = vA0 + s*32768, va1 = vA1 + s*32768;
    const uint32_t vb0 = vB0 + s*32768, vb1 = vB1 + s*32768;
    // h B-operand frags for this K-tile (L2-resident 64KB table)
    short8 c2[2];
    c2[0] = *(const short8*)(c2p + t*64);
    c2[1] = *(const short8*)(c2p + t*64 + 32);
    // ---- ph0: read A fm0-3 + B fn0-1; stage A(t+1)h0; vmcnt(2) ----
    DSRO(a[0], va0, "0");    DSRO(a[1], va1, "0");
    DSRO(a[2], va0, "2048"); DSRO(a[3], va1, "2048");
    DSRO(a[4], va0, "4096"); DSRO(a[5], va1, "4096");
    DSRO(a[6], va0, "6144"); DSRO(a[7], va1, "6144");
    DSRO(b0[0], vb0, "0");    DSRO(b0[1], vb1, "0");
    DSRO(b0[2], vb0, "2048"); DSRO(b0[3], vb1, "2048");
    if (t < 15){ STG_A(t+1, 0, sn); asm volatile("s_waitcnt vmcnt(2)" ::: "memory"); }
    else       {                    asm volatile("s_waitcnt vmcnt(0)" ::: "memory"); }
    __builtin_amdgcn_s_barrier();
    asm volatile("s_waitcnt lgkmcnt(0)" ::: "memory");
    __builtin_amdgcn_sched_barrier(0);
    __builtin_amdgcn_s_setprio(1);
    #pragma unroll
    for (int kk=0;kk<2;kk++)
      #pragma unroll
      for (int fm=0;fm<4;fm++)
        #pragma unroll
        for (int fn=0;fn<2;fn++)
          acc[fm][fn] = __builtin_amdgcn_mfma_f32_16x16x32_bf16(a[fm*2+kk], b0[fn*2+kk], acc[fm][fn], 0, 0, 0);
    __builtin_amdgcn_s_setprio(0);
    __builtin_amdgcn_s_barrier();
    // ---- ph1: read B fn2-3; stage A(t+1)h1; h-MFMA (wn<2, rows wm*128+0..63) ----
    DSRO(b1[0], vb0, "4096"); DSRO(b1[1], vb1, "4096");
    DSRO(b1[2], vb0, "6144"); DSRO(b1[3], vb1, "6144");
    if (t < 15) STG_A(t+1, 1, sn);
    __builtin_amdgcn_s_barrier();
    asm volatile("s_waitcnt lgkmcnt(0)" ::: "memory");
    __builtin_amdgcn_sched_barrier(0);
    __builtin_amdgcn_s_setprio(1);
    #pragma unroll
    for (int kk=0;kk<2;kk++)
      #pragma unroll
      for (int fm=0;fm<4;fm++)
        #pragma unroll
        for (int fn=0;fn<2;fn++)
          acc[fm][2+fn] = __builtin_amdgcn_mfma_f32_16x16x32_bf16(a[fm*2+kk], b1[fn*2+kk], acc[fm][2+fn], 0, 0, 0);
    if (wn < 2){
      #pragma unroll
      for (int kk=0;kk<2;kk++)
        #pragma unroll
        for (int f=0;f<4;f++)
          acc_h[f] = __builtin_amdgcn_mfma_f32_16x16x32_bf16(a[f*2+kk], c2[kk], acc_h[f], 0, 0, 0);
    }
    __builtin_amdgcn_s_setprio(0);
    __builtin_amdgcn_s_barrier();
    // ---- ph2: read A fm4-7; stage B(t+1)h0 ----
    DSRO(a[0], va0, "8192");  DSRO(a[1], va1, "8192");
    DSRO(a[2], va0, "10240"); DSRO(a[3], va1, "10240");
    DSRO(a[4], va0, "12288"); DSRO(a[5], va1, "12288");
    DSRO(a[6], va0, "14336"); DSRO(a[7], va1, "14336");
    if (t < 15) STG_B(t+1, 0, sn);
    __builtin_amdgcn_s_barrier();
    asm volatile("s_waitcnt lgkmcnt(0)" ::: "memory");
    __builtin_amdgcn_sched_barrier(0);
    __builtin_amdgcn_s_setprio(1);
    #pragma unroll
    for (int kk=0;kk<2;kk++)
      #pragma unroll
      for (int fm=0;fm<4;fm++)
        #pragma unroll
        for (int fn=0;fn<2;fn++)
          acc[4+fm][2+fn] = __builtin_amdgcn_mfma_f32_16x16x32_bf16(a[fm*2+kk], b1[fn*2+kk], acc[4+fm][2+fn], 0, 0, 0);
    __builtin_amdgcn_s_setprio(0);
    __builtin_amdgcn_s_barrier();
    // ---- ph3: stage B(t+1)h1; vmcnt(2); h-MFMA (wn>=2, rows wm*128+64..127) ----
    if (t < 15){ STG_B(t+1, 1, sn); asm volatile("s_waitcnt vmcnt(2)" ::: "memory"); }
    __builtin_amdgcn_s_barrier();
    __builtin_amdgcn_s_setprio(1);
    #pragma unroll
    for (int kk=0;kk<2;kk++)
      #pragma unroll
      for (int fm=0;fm<4;fm++)
        #pragma unroll
        for (int fn=0;fn<2;fn++)
          acc[4+fm][fn] = __builtin_amdgcn_mfma_f32_16x16x32_bf16(a[fm*2+kk], b0[fn*2+kk], acc[4+fm][fn], 0, 0, 0);
    if (wn >= 2){
      #pragma unroll
      for (int kk=0;kk<2;kk++)
        #pragma unroll
        for (int f=0;f<4;f++)
          acc_h[f] = __builtin_amdgcn_mfma_f32_16x16x32_bf16(a[f*2+kk], c2[kk], acc_h[f], 0, 0, 0);
    }
    __builtin_amdgcn_s_setprio(0);
    __builtin_amdgcn_s_barrier();
  }

  // ---- epilogue: gate -> LDS, HG = h*gate -> LDS, LoRA MFMA ----
  __syncthreads();
  {
    float4* gl4 = (float4*)(ldsc + 24576);           // 256 x 8 f32 = 8KB
    gl4[tid] = ((const float4*)(gate + (size_t)m0*8))[tid];
  }
  __syncthreads();
  unsigned short* HGl = (unsigned short*)ldsc;        // [256][40] u16 (pad 40)
  const float*    gl  = (const float*)(ldsc + 24576);
  {
    const int rbase = wm*128 + (wn>>1)*64;
    const int n = (wn&1)*16 + lrow;
    #pragma unroll
    for (int f=0; f<4; f++)
      #pragma unroll
      for (int j=0;j<4;j++){
        int row = rbase + f*16 + q*4 + j;
        HGl[row*40 + n] = f2bf(acc_h[f][j] * gl[row*8 + (n>>2)]);
      }
  }
  __syncthreads();
  {
    short8 hb[4];
    #pragma unroll
    for (int fn=0; fn<4; fn++)
      hb[fn] = *(const short8*)(BTt + (size_t)(n0 + wn*64 + fn*16 + lrow)*32 + q*8);
    #pragma unroll
    for (int fm=0; fm<8; fm++){
      short8 ha = *(const short8*)((const char*)HGl + (size_t)(wm*128 + fm*16 + lrow)*80 + q*16);
      #pragma unroll
      for (int fn=0; fn<4; fn++)
        acc[fm][fn] = __builtin_amdgcn_mfma_f32_16x16x32_bf16(ha, hb[fn], acc[fm][fn], 0, 0, 0);
    }
  }

  // ---- store: + bias ----
  #pragma unroll
  for (int fn=0;fn<4;fn++){
    int col = n0 + wn*64 + fn*16 + lrow;
    float bv = bias[col];
    #pragma unroll
    for (int fm=0;fm<8;fm++){
      int rb = m0 + wm*128 + fm*16 + q*4;
      #pragma unroll
      for (int j=0;j<4;j++)
        out[(size_t)(rb+j)*1024 + col] = acc[fm][fn][j] + bv;
    }
  }
#undef STG_A
#undef STG_B
}

// ---------------- host ---------------------------------------------------
extern "C" void kernel_launch(void* const* d_in, const int* in_sizes, int n_in,
                              void* d_out, int out_size, void* d_ws, size_t ws_size,
                              hipStream_t stream){
  const float* x  = (const float*)d_in[0];
  const float* W  = (const float*)d_in[1];
  const float* bb = (const float*)d_in[2];
  const float* Wr = (const float*)d_in[3];
  const float* A  = (const float*)d_in[4];
  const float* Bm = (const float*)d_in[5];
  float* out = (float*)d_out;
  char* ws = (char*)d_ws;

  // ws layout: Wb 2MB | BTt 64KB | W2b 64KB | gate 512KB | xb 32MB
  unsigned short* Wb   = (unsigned short*)(ws + 0);
  unsigned short* BTt  = (unsigned short*)(ws + 2097152);
  unsigned short* W2b  = (unsigned short*)(ws + 2162688);
  float*          gate = (float*)         (ws + 2228224);
  unsigned short* xb   = (unsigned short*)(ws + 2752512);

  kconv<<<4096, 256, 0, stream>>>(W, A, Bm, Wb, BTt, W2b);
  kxl2<<<512, 256, 0, stream>>>(x, Wr, xb, gate);
  kgemm6<<<256, 512, 0, stream>>>(xb, Wb, BTt, W2b, gate, bb, out);
}

// Round 7
// 82.015 us; speedup vs baseline: 5.3867x; 1.0590x over previous
//
#include <hip/hip_runtime.h>
#include <cstdint>

typedef __attribute__((ext_vector_type(8))) short short8;
typedef __attribute__((ext_vector_type(4))) float f32x4;

__device__ inline unsigned short f2bf(float f){
  union { float f; uint32_t u; } v; v.f = f;
  uint32_t r = v.u + 0x7FFFu + ((v.u >> 16) & 1u);
  return (unsigned short)(r >> 16);
}

#define GLL(gp, lp) __builtin_amdgcn_global_load_lds(              \
    (const __attribute__((address_space(1))) void*)(gp),           \
    (__attribute__((address_space(3))) void*)(lp), 16, 0, 0)

#define DSRO(dst, addr, off) \
  asm volatile("ds_read_b128 %0, %1 offset:" off : "=v"(dst) : "v"(addr))
#define GLD16(dst, ptr) \
  asm volatile("global_load_dwordx4 %0, %1, off" : "=v"(dst) : "v"(ptr) : "memory")

// ---------------- kernel 1: weight conversions --------------------------
__global__ __launch_bounds__(256) void kconv(const float* __restrict__ W,
                                             const float* __restrict__ A,
                                             const float* __restrict__ Bm,
                                             unsigned short* __restrict__ Wb,
                                             unsigned short* __restrict__ BTt,
                                             unsigned short* __restrict__ W2b){
  int i = blockIdx.x * 256 + threadIdx.x;
  Wb[i] = f2bf(W[i]);
  if (i < 32768){
    int o = i >> 5, c = i & 31;
    BTt[i] = f2bf(Bm[(size_t)c*1024 + o]);
    int n = i >> 10, d = i & 1023;
    W2b[i] = f2bf(A[(((size_t)(n>>2))*1024 + d)*4 + (n&3)]);
  }
}

// ---------------- kernel 2: x->bf16 + f32 router + gating ---------------
__global__ __launch_bounds__(256) void kxl2(const float* __restrict__ x,
                                            const float* __restrict__ Wr,
                                            unsigned short* __restrict__ xb,
                                            float* __restrict__ gate){
  __shared__ float wr[8192];
  const int tid  = threadIdx.x;
  const int lane = tid & 63;
  const int wid  = tid >> 6;
  {
    const float4* s  = (const float4*)Wr;
    float4*       d4 = (float4*)wr;
    #pragma unroll
    for (int j=0;j<8;j++) d4[j*256+tid] = s[j*256+tid];
  }
  __syncthreads();
  const int tk  = lane >> 3, ln8 = lane & 7;
  const size_t tok = (size_t)blockIdx.x*32 + wid*8 + tk;
  const float4* xr = (const float4*)(x + tok*1024);
  ushort4*      xd = (ushort4*)(xb + tok*1024);
  const float4* wv = (const float4*)wr;
  float p[8] = {0.f,0.f,0.f,0.f,0.f,0.f,0.f,0.f};
  #pragma unroll 4
  for (int it=0; it<32; it++){
    float4 v = xr[it*8 + ln8];
    ushort4 o; o.x=f2bf(v.x); o.y=f2bf(v.y); o.z=f2bf(v.z); o.w=f2bf(v.w);
    xd[it*8 + ln8] = o;
    #pragma unroll
    for (int e=0;e<8;e++){
      float4 wq = wv[e*256 + it*8 + ln8];
      p[e] += v.x*wq.x + v.y*wq.y + v.z*wq.z + v.w*wq.w;
    }
  }
  #pragma unroll
  for (int off=1; off<8; off<<=1){
    #pragma unroll
    for (int e=0;e<8;e++) p[e] += __shfl_xor(p[e], off, 64);
  }
  if (ln8 == 0){
    float mx = p[0];
    #pragma unroll
    for (int e=1;e<8;e++) mx = fmaxf(mx, p[e]);
    float ex[8], s2 = 0.f;
    #pragma unroll
    for (int e=0;e<8;e++){ ex[e] = __expf(p[e]-mx); s2 += ex[e]; }
    int i1 = 0; float v1 = ex[0];
    #pragma unroll
    for (int e=1;e<8;e++) if (ex[e] > v1){ v1 = ex[e]; i1 = e; }
    int i2 = -1; float v2 = -1.f;
    #pragma unroll
    for (int e=0;e<8;e++) if (e != i1 && ex[e] > v2){ v2 = ex[e]; i2 = e; }
    float g1 = v1/s2, g2 = v2/s2;
    float rs = 1.f/(g1 + g2 + 1e-6f);
    float* go = gate + tok*8;
    #pragma unroll
    for (int e=0;e<8;e++) go[e] = (e==i1 ? g1 : (e==i2 ? g2 : 0.f)) * rs;
  }
}

// ---------------- kernel 3: fused 256x256 GEMM + h-MFMA + LoRA ----------
// asm ds_read + split lgkmcnt clusters; c2 (W2b frags) via asm global loads
// pipelined one tile ahead; traced vmcnt: ph0 vmcnt(2) drains B(t) before
// b0 reads issue; ph3 vmcnt(4) drains A(t+1)+c2, leaves B(t+1) in flight.
__global__ __launch_bounds__(512, 2) void kgemm6(const unsigned short* __restrict__ xb,
                                                 const unsigned short* __restrict__ Wb,
                                                 const unsigned short* __restrict__ BTt,
                                                 const unsigned short* __restrict__ W2b,
                                                 const float* __restrict__ gate,
                                                 const float* __restrict__ bias,
                                                 float* __restrict__ out){
  __shared__ __attribute__((aligned(128))) char lds[131072]; // A@0/32K, B@64K/96K
  char* ldsc = lds;
  const uint32_t L = (uint32_t)(uintptr_t)lds;
  const int tid  = threadIdx.x;
  const int lane = tid & 63;
  const int w    = tid >> 6;
  const int mblk = blockIdx.x & 63;      // same-mblk blocks -> same XCD
  const int nblk = blockIdx.x >> 6;
  const int m0 = mblk << 8, n0 = nblk << 8;
  const int wm = w >> 2, wn = w & 3;
  const int lrow = lane & 15;
  const int q    = lane >> 4;

  const int swzk = (lrow & 7) << 4;
  const uint32_t vA0 = L + (uint32_t)(wm*128 + lrow)*128 + (uint32_t)((q<<4) ^ swzk);
  const uint32_t vA1 = L + (uint32_t)(wm*128 + lrow)*128 + (uint32_t)(((q^4)<<4) ^ swzk);
  const uint32_t vB0 = L + 65536u + (uint32_t)(wn*64 + lrow)*128 + (uint32_t)((q<<4) ^ swzk);
  const uint32_t vB1 = L + 65536u + (uint32_t)(wn*64 + lrow)*128 + (uint32_t)(((q^4)<<4) ^ swzk);

  const int rowL = lane >> 3;
  const int colb = ((lane & 7) ^ rowL) << 4;
  const int rbA = (w>>2)*128 + (w&3)*16;
  const int rbB = (w>>1)*64 + (w&1)*16;
  const char* Ag = (const char*)xb + ((size_t)(m0 + rbA + rowL) << 11) + colb;
  const char* Bg = (const char*)Wb + ((size_t)(n0 + rbB + rowL) << 11) + colb;

#define STG_A(tt, h, ss) do{                                                    \
    GLL(Ag + (size_t)(h)*131072 + (tt)*128,                                     \
        ldsc + (ss)*32768 + (rbA + (h)*64)*128 + lane*16);                      \
    GLL(Ag + (size_t)(h)*131072 + 16384 + (tt)*128,                             \
        ldsc + (ss)*32768 + (rbA + (h)*64 + 8)*128 + lane*16); }while(0)
#define STG_B(tt, h, ss) do{                                                    \
    GLL(Bg + (size_t)(h)*65536 + (tt)*128,                                      \
        ldsc + 65536 + (ss)*32768 + (rbB + (h)*32)*128 + lane*16);              \
    GLL(Bg + (size_t)(h)*65536 + 16384 + (tt)*128,                              \
        ldsc + 65536 + (ss)*32768 + (rbB + (h)*32 + 8)*128 + lane*16); }while(0)

  f32x4 acc[8][4];
  #pragma unroll
  for (int a2=0;a2<8;a2++)
    #pragma unroll
    for (int b2=0;b2<4;b2++) acc[a2][b2] = (f32x4){0.f,0.f,0.f,0.f};
  f32x4 acc_h[4];
  #pragma unroll
  for (int f=0; f<4; f++) acc_h[f] = (f32x4){0.f,0.f,0.f,0.f};

  // W2b frag base: row (wn&1)*16 + lrow, k-offset q*8  (byte step/tile = 128)
  const unsigned short* c2p = W2b + (size_t)((wn&1)*16 + lrow)*1024 + q*8;
  short8 c2cur0, c2cur1, c2nxt0, c2nxt1;

  // prologue: tile0 fully + c2cur
  STG_A(0,0,0); STG_A(0,1,0); STG_B(0,0,0); STG_B(0,1,0);
  GLD16(c2cur0, c2p);
  GLD16(c2cur1, c2p + 32);
  asm volatile("s_waitcnt vmcnt(0)" ::: "memory");
  __builtin_amdgcn_sched_barrier(0);
  __builtin_amdgcn_s_barrier();

  short8 a[8], b0[4], b1[4];
  #pragma unroll 1
  for (int t = 0; t < 16; ++t){
    const int s = t & 1, sn = s ^ 1;
    const uint32_t va0 = vA0 + s*32768, va1 = vA1 + s*32768;
    const uint32_t vb0 = vB0 + s*32768, vb1 = vB1 + s*32768;
    // ---- ph0: read A fm0-3(x2kk) [safe: drained last ph3]; STG_A(t+1,0);
    //          vmcnt(2) drains ALL B(t); then b0 reads; barrier ----
    DSRO(a[0], va0, "0");    DSRO(a[1], va1, "0");
    DSRO(a[2], va0, "2048"); DSRO(a[3], va1, "2048");
    DSRO(a[4], va0, "4096"); DSRO(a[5], va1, "4096");
    DSRO(a[6], va0, "6144"); DSRO(a[7], va1, "6144");
    if (t < 15){ STG_A(t+1, 0, sn); asm volatile("s_waitcnt vmcnt(2)" ::: "memory"); }
    else       {                    asm volatile("s_waitcnt vmcnt(0)" ::: "memory"); }
    __builtin_amdgcn_sched_barrier(0);
    DSRO(b0[0], vb0, "0");    DSRO(b0[1], vb1, "0");
    DSRO(b0[2], vb0, "2048"); DSRO(b0[3], vb1, "2048");
    __builtin_amdgcn_s_barrier();
    asm volatile("s_waitcnt lgkmcnt(2)" ::: "memory");   // a[0..7], b0[0..1] ready
    __builtin_amdgcn_sched_barrier(0);
    __builtin_amdgcn_s_setprio(1);
    #pragma unroll
    for (int kk=0;kk<2;kk++)
      #pragma unroll
      for (int fm=0;fm<4;fm++)
        acc[fm][0] = __builtin_amdgcn_mfma_f32_16x16x32_bf16(a[fm*2+kk], b0[kk], acc[fm][0], 0, 0, 0);
    asm volatile("s_waitcnt lgkmcnt(0)" ::: "memory");
    __builtin_amdgcn_sched_barrier(0);
    #pragma unroll
    for (int kk=0;kk<2;kk++)
      #pragma unroll
      for (int fm=0;fm<4;fm++)
        acc[fm][1] = __builtin_amdgcn_mfma_f32_16x16x32_bf16(a[fm*2+kk], b0[2+kk], acc[fm][1], 0, 0, 0);
    __builtin_amdgcn_s_setprio(0);
    __builtin_amdgcn_s_barrier();
    // ---- ph1: read b1; STG_A(t+1,1); c2nxt; MFMA fn2-3 + h (wn<2) ----
    DSRO(b1[0], vb0, "4096"); DSRO(b1[1], vb1, "4096");
    DSRO(b1[2], vb0, "6144"); DSRO(b1[3], vb1, "6144");
    if (t < 15){
      STG_A(t+1, 1, sn);
      GLD16(c2nxt0, c2p + (t+1)*64);
      GLD16(c2nxt1, c2p + (t+1)*64 + 32);
    }
    __builtin_amdgcn_s_barrier();
    asm volatile("s_waitcnt lgkmcnt(2)" ::: "memory");   // b1[0..1] ready
    __builtin_amdgcn_sched_barrier(0);
    __builtin_amdgcn_s_setprio(1);
    #pragma unroll
    for (int kk=0;kk<2;kk++)
      #pragma unroll
      for (int fm=0;fm<4;fm++)
        acc[fm][2] = __builtin_amdgcn_mfma_f32_16x16x32_bf16(a[fm*2+kk], b1[kk], acc[fm][2], 0, 0, 0);
    asm volatile("s_waitcnt lgkmcnt(0)" ::: "memory");
    __builtin_amdgcn_sched_barrier(0);
    #pragma unroll
    for (int kk=0;kk<2;kk++)
      #pragma unroll
      for (int fm=0;fm<4;fm++)
        acc[fm][3] = __builtin_amdgcn_mfma_f32_16x16x32_bf16(a[fm*2+kk], b1[2+kk], acc[fm][3], 0, 0, 0);
    if (wn < 2){
      #pragma unroll
      for (int f=0;f<4;f++){
        acc_h[f] = __builtin_amdgcn_mfma_f32_16x16x32_bf16(a[f*2],   c2cur0, acc_h[f], 0, 0, 0);
        acc_h[f] = __builtin_amdgcn_mfma_f32_16x16x32_bf16(a[f*2+1], c2cur1, acc_h[f], 0, 0, 0);
      }
    }
    __builtin_amdgcn_s_setprio(0);
    __builtin_amdgcn_s_barrier();
    // ---- ph2: read A fm4-7; STG_B(t+1,0); MFMA fm4-7 x fn2-3 ----
    DSRO(a[0], va0, "8192");  DSRO(a[1], va1, "8192");
    DSRO(a[2], va0, "10240"); DSRO(a[3], va1, "10240");
    DSRO(a[4], va0, "12288"); DSRO(a[5], va1, "12288");
    DSRO(a[6], va0, "14336"); DSRO(a[7], va1, "14336");
    if (t < 15) STG_B(t+1, 0, sn);
    __builtin_amdgcn_s_barrier();
    asm volatile("s_waitcnt lgkmcnt(4)" ::: "memory");   // a[0..3] ready
    __builtin_amdgcn_sched_barrier(0);
    __builtin_amdgcn_s_setprio(1);
    #pragma unroll
    for (int kk=0;kk<2;kk++)
      #pragma unroll
      for (int fm=0;fm<2;fm++)
        #pragma unroll
        for (int fn=0;fn<2;fn++)
          acc[4+fm][2+fn] = __builtin_amdgcn_mfma_f32_16x16x32_bf16(a[fm*2+kk], b1[fn*2+kk], acc[4+fm][2+fn], 0, 0, 0);
    asm volatile("s_waitcnt lgkmcnt(0)" ::: "memory");
    __builtin_amdgcn_sched_barrier(0);
    #pragma unroll
    for (int kk=0;kk<2;kk++)
      #pragma unroll
      for (int fm=2;fm<4;fm++)
        #pragma unroll
        for (int fn=0;fn<2;fn++)
          acc[4+fm][2+fn] = __builtin_amdgcn_mfma_f32_16x16x32_bf16(a[fm*2+kk], b1[fn*2+kk], acc[4+fm][2+fn], 0, 0, 0);
    __builtin_amdgcn_s_setprio(0);
    __builtin_amdgcn_s_barrier();
    // ---- ph3: STG_B(t+1,1); vmcnt(4): A(t+1)+c2 drained, B(t+1) in flight;
    //          MFMA fm4-7 x fn0-1 + h (wn>=2) ----
    if (t < 15){
      STG_B(t+1, 1, sn);
      asm volatile("s_waitcnt vmcnt(4)" ::: "memory");
    }
    __builtin_amdgcn_sched_barrier(0);
    __builtin_amdgcn_s_barrier();
    __builtin_amdgcn_s_setprio(1);
    #pragma unroll
    for (int kk=0;kk<2;kk++)
      #pragma unroll
      for (int fm=0;fm<4;fm++)
        #pragma unroll
        for (int fn=0;fn<2;fn++)
          acc[4+fm][fn] = __builtin_amdgcn_mfma_f32_16x16x32_bf16(a[fm*2+kk], b0[fn*2+kk], acc[4+fm][fn], 0, 0, 0);
    if (wn >= 2){
      #pragma unroll
      for (int f=0;f<4;f++){
        acc_h[f] = __builtin_amdgcn_mfma_f32_16x16x32_bf16(a[f*2],   c2cur0, acc_h[f], 0, 0, 0);
        acc_h[f] = __builtin_amdgcn_mfma_f32_16x16x32_bf16(a[f*2+1], c2cur1, acc_h[f], 0, 0, 0);
      }
    }
    __builtin_amdgcn_s_setprio(0);
    __builtin_amdgcn_s_barrier();
    c2cur0 = c2nxt0; c2cur1 = c2nxt1;
  }

  // ---- epilogue: gate -> LDS, HG = h*gate -> LDS (72B stride), LoRA ----
  __syncthreads();
  {
    float4* gl4 = (float4*)(ldsc + 20480);              // 256 tok x 8 f32 = 8KB
    gl4[tid] = ((const float4*)(gate + (size_t)m0*8))[tid];
  }
  __syncthreads();
  unsigned short* HGl = (unsigned short*)ldsc;           // [256][36] u16, 72B rows
  const float*    gl  = (const float*)(ldsc + 20480);
  {
    const int rbase = wm*128 + (wn>>1)*64;
    const int n = (wn&1)*16 + lrow;
    #pragma unroll
    for (int f=0; f<4; f++)
      #pragma unroll
      for (int j=0;j<4;j++){
        int row = rbase + f*16 + q*4 + j;
        HGl[row*36 + n] = f2bf(acc_h[f][j] * gl[row*8 + (n>>2)]);
      }
  }
  __syncthreads();
  {
    short8 hb[4];
    #pragma unroll
    for (int fn=0; fn<4; fn++)
      hb[fn] = *(const short8*)(BTt + (size_t)(n0 + wn*64 + fn*16 + lrow)*32 + q*8);
    #pragma unroll
    for (int fm=0; fm<8; fm++){
      short8 ha = *(const short8*)((const char*)HGl + (size_t)(wm*128 + fm*16 + lrow)*72 + q*16);
      #pragma unroll
      for (int fn=0; fn<4; fn++)
        acc[fm][fn] = __builtin_amdgcn_mfma_f32_16x16x32_bf16(ha, hb[fn], acc[fm][fn], 0, 0, 0);
    }
  }

  // ---- store: + bias ----
  #pragma unroll
  for (int fn=0;fn<4;fn++){
    int col = n0 + wn*64 + fn*16 + lrow;
    float bv = bias[col];
    #pragma unroll
    for (int fm=0;fm<8;fm++){
      int rb = m0 + wm*128 + fm*16 + q*4;
      #pragma unroll
      for (int j=0;j<4;j++)
        out[(size_t)(rb+j)*1024 + col] = acc[fm][fn][j] + bv;
    }
  }
#undef STG_A
#undef STG_B
}

// ---------------- host ---------------------------------------------------
extern "C" void kernel_launch(void* const* d_in, const int* in_sizes, int n_in,
                              void* d_out, int out_size, void* d_ws, size_t ws_size,
                              hipStream_t stream){
  const float* x  = (const float*)d_in[0];
  const float* W  = (const float*)d_in[1];
  const float* bb = (const float*)d_in[2];
  const float* Wr = (const float*)d_in[3];
  const float* A  = (const float*)d_in[4];
  const float* Bm = (const float*)d_in[5];
  float* out = (float*)d_out;
  char* ws = (char*)d_ws;

  // ws layout: Wb 2MB | BTt 64KB | W2b 64KB | gate 512KB | xb 32MB
  unsigned short* Wb   = (unsigned short*)(ws + 0);
  unsigned short* BTt  = (unsigned short*)(ws + 2097152);
  unsigned short* W2b  = (unsigned short*)(ws + 2162688);
  float*          gate = (float*)         (ws + 2228224);
  unsigned short* xb   = (unsigned short*)(ws + 2752512);

  kconv<<<4096, 256, 0, stream>>>(W, A, Bm, Wb, BTt, W2b);
  kxl2<<<512, 256, 0, stream>>>(x, Wr, xb, gate);
  kgemm6<<<256, 512, 0, stream>>>(xb, Wb, BTt, W2b, gate, bb, out);
}